// Round 11
// baseline (1331.896 us; speedup 1.0000x reference)
//
#include <hip/hip_runtime.h>
#include <cmath>

#define B_ 2
#define K_ 384
#define N_ 4096
#define D_ 1024
#define H_ 150
#define L_ 12
#define NB_ 10
#define LDW_S 164   // padded ldw row stride (164 % 32 = 4 dwords -> buckets on distinct banks)

typedef unsigned short u16;
typedef __bf16 bf16x8 __attribute__((ext_vector_type(8)));
typedef float f32x4 __attribute__((ext_vector_type(4)));

__device__ __forceinline__ u16 f2bf(float f){
  unsigned u = __builtin_bit_cast(unsigned, f);
  unsigned r = (u + 0x7FFFu + ((u >> 16) & 1u)) >> 16;
  return (u16)r;
}
__device__ __forceinline__ float bf2f(u16 h){
  unsigned u = ((unsigned)h) << 16;
  return __builtin_bit_cast(float, u);
}
__device__ __forceinline__ int bucketf(int d){
  int da = d < 0 ? -d : d;
  if (da <= 4) return da;
  int lg = 31 - __clz(da);
  int v = lg + 3;
  return v > NB_ - 1 ? NB_ - 1 : v;
}

// ---------------- transpose fp32 (Kd x Nd) -> bf16 (Nd x Kd), out row stride = ostride
__global__ void transpose_f2bf(const float* __restrict__ in, u16* __restrict__ out,
                               int Kd, int Nd, int ostride){
  __shared__ float t[32][33];
  int bx = blockIdx.x * 32, by = blockIdx.y * 32;
  int tx = threadIdx.x, ty = threadIdx.y;
  for (int i = 0; i < 32; i += 8){
    int k = by + ty + i, n = bx + tx;
    t[ty + i][tx] = (k < Kd && n < Nd) ? in[(size_t)k * Nd + n] : 0.f;
  }
  __syncthreads();
  for (int i = 0; i < 32; i += 8){
    int n = bx + ty + i, k = by + tx;
    if (n < Nd && k < Kd) out[(size_t)n * ostride + k] = f2bf(t[tx][ty + i]);
  }
}

// ---------------- transpose bf16 (K_ x D_) -> (D_ x K_) per batch
__global__ void transpose_bf(const u16* __restrict__ in, u16* __restrict__ out){
  __shared__ u16 t[32][34];
  int b = blockIdx.z;
  const u16* I = in + (size_t)b * K_ * D_;
  u16* O = out + (size_t)b * D_ * K_;
  int bx = blockIdx.x * 32, by = blockIdx.y * 32;  // bx: d, by: k
  int tx = threadIdx.x, ty = threadIdx.y;
  for (int i = 0; i < 32; i += 8) t[ty + i][tx] = I[(size_t)(by + ty + i) * D_ + bx + tx];
  __syncthreads();
  for (int i = 0; i < 32; i += 8) O[(size_t)(bx + ty + i) * K_ + by + tx] = t[tx][ty + i];
}

// ---------------- small setup: dW = dist_emb @ Wd + bd ; blr = [bl|br] ; WoT bf16 [16][160]
__global__ void small_setup(const float* __restrict__ dist_emb, const float* __restrict__ Wd,
                            const float* __restrict__ bd, const float* __restrict__ bl,
                            const float* __restrict__ br, const float* __restrict__ Wo,
                            float* __restrict__ dWg, float* __restrict__ blr,
                            u16* __restrict__ woT){
  int tid = threadIdx.x;
  for (int idx = tid; idx < NB_ * H_; idx += 256){
    int nb = idx / H_, h = idx - nb * H_;
    float s = bd[h];
    for (int dd = 0; dd < 20; ++dd) s += dist_emb[nb * 20 + dd] * Wd[dd * H_ + h];
    dWg[idx] = s;
  }
  for (int idx = tid; idx < H_; idx += 256){
    blr[idx] = bl[idx];
    blr[H_ + idx] = br[idx];
  }
  for (int idx = tid; idx < 16 * 160; idx += 256){
    int l = idx / 160, t = idx - l * 160;
    float w = (l < L_ && t < H_) ? Wo[t * L_ + l] : 0.f;
    woT[idx] = f2bf(w);
  }
}

// ---------------- fp32 -> bf16 elementwise (n divisible by 4)
__global__ void cvt_f32_bf16(const float* __restrict__ in, u16* __restrict__ out, int n){
  int idx = (blockIdx.x * 256 + threadIdx.x) * 4;
  if (idx < n){
    float4 v = *(const float4*)(in + idx);
    ushort4 o;
    o.x = f2bf(v.x); o.y = f2bf(v.y); o.z = f2bf(v.z); o.w = f2bf(v.w);
    *(ushort4*)(out + idx) = o;
  }
}

// ---------------- init lr (stride 320): l bias [0,150), r bias [160,310), zeros elsewhere
__global__ void init_lr(const float* __restrict__ blr, float* __restrict__ lr){
  int idx = blockIdx.x * 256 + threadIdx.x;
  if (idx >= (B_ * K_) * 320) return;
  int col = idx % 320;
  float v = 0.f;
  if (col < 150) v = blr[col];
  else if (col >= 160 && col < 310) v = blr[150 + (col - 160)];
  lr[idx] = v;
}

// ---------------- bf16 MFMA GEMM (32x64 tile), split-K atomic into Out (no epilogue)
__global__ __launch_bounds__(256)
void gemm_part_atomic32(const u16* __restrict__ A0, const u16* __restrict__ A1,
                        const u16* __restrict__ A2, const u16* __restrict__ BT,
                        int Ktot, int klen, float* __restrict__ Out, int ldo){
  __shared__ u16 As[32][72];
  __shared__ u16 Bs[64][72];
  int tid = threadIdx.x;
  int m0 = blockIdx.x * 32, n0 = blockIdx.y * 64;
  int s = blockIdx.z;
  int kbeg = s * klen, kend = kbeg + klen;
  int wave = tid >> 6, lane = tid & 63;
  int wm = wave >> 1, wn = wave & 1;
  int q = lane >> 4, mr = lane & 15;
  f32x4 acc[2] = {{0.f,0.f,0.f,0.f},{0.f,0.f,0.f,0.f}};
  const u16* Achunks[3] = {A0, A1, A2};
  for (int k0 = kbeg; k0 < kend; k0 += 64){
    const u16* Ap = Achunks[k0 >> 10] + (k0 & 1023);
    {
      int row = tid >> 3, c8 = tid & 7;
      *(uint4*)&As[row][c8 * 8] = *(const uint4*)&Ap[(size_t)(m0 + row) * 1024 + c8 * 8];
    }
    for (int c = tid; c < 512; c += 256){
      int row = c >> 3, c8 = c & 7;
      *(uint4*)&Bs[row][c8 * 8] = *(const uint4*)&BT[(size_t)(n0 + row) * Ktot + k0 + c8 * 8];
    }
    __syncthreads();
#pragma unroll
    for (int ks = 0; ks < 64; ks += 32){
      bf16x8 a  = *(const bf16x8*)&As[wm * 16 + mr][ks + q * 8];
      bf16x8 b0 = *(const bf16x8*)&Bs[wn * 32 + mr][ks + q * 8];
      bf16x8 b1 = *(const bf16x8*)&Bs[wn * 32 + 16 + mr][ks + q * 8];
      acc[0] = __builtin_amdgcn_mfma_f32_16x16x32_bf16(a, b0, acc[0], 0, 0, 0);
      acc[1] = __builtin_amdgcn_mfma_f32_16x16x32_bf16(a, b1, acc[1], 0, 0, 0);
    }
    __syncthreads();
  }
#pragma unroll
  for (int nt = 0; nt < 2; ++nt){
    int col = n0 + wn * 32 + nt * 16 + mr;
#pragma unroll
    for (int r = 0; r < 4; ++r){
      int row = m0 + wm * 16 + q * 4 + r;
      atomicAdd(&Out[(size_t)row * ldo + col], acc[nt][r]);
    }
  }
}

// ---------------- bf16 MFMA GEMM (32x64 tile), split-K atomic + FUSED epilogue
// Last split-K block per tile (atomic counter) applies the activation, writes outputs,
// re-zeros its accF tile and resets its counter (self-sustaining across graph replays).
// mode 1: outH = bf16(tanh(sum)); mode 2: outH = bf16(sum);
// mode 3: g = sigmoid(sum+bias); un = g*uin + (1-g)*ctxtin; outF fp32 + outH bf16.
__global__ __launch_bounds__(256)
void gemm_fused(const u16* __restrict__ A0, const u16* __restrict__ A1,
                const u16* __restrict__ A2, const u16* __restrict__ BT,
                int Ktot, int klen, float* __restrict__ accF,
                int* __restrict__ ctr, int S, int mode,
                const float* __restrict__ bias, float* __restrict__ outF,
                u16* __restrict__ outH, const float* __restrict__ uin,
                const u16* __restrict__ ctxtin){
  __shared__ u16 As[32][72];
  __shared__ u16 Bs[64][72];
  int tid = threadIdx.x;
  int m0 = blockIdx.x * 32, n0 = blockIdx.y * 64;
  int s = blockIdx.z;
  int kbeg = s * klen, kend = kbeg + klen;
  int wave = tid >> 6, lane = tid & 63;
  int wm = wave >> 1, wn = wave & 1;
  int q = lane >> 4, mr = lane & 15;
  f32x4 acc[2] = {{0.f,0.f,0.f,0.f},{0.f,0.f,0.f,0.f}};
  const u16* Achunks[3] = {A0, A1, A2};
  for (int k0 = kbeg; k0 < kend; k0 += 64){
    const u16* Ap = Achunks[k0 >> 10] + (k0 & 1023);
    {
      int row = tid >> 3, c8 = tid & 7;
      *(uint4*)&As[row][c8 * 8] = *(const uint4*)&Ap[(size_t)(m0 + row) * 1024 + c8 * 8];
    }
    for (int c = tid; c < 512; c += 256){
      int row = c >> 3, c8 = c & 7;
      *(uint4*)&Bs[row][c8 * 8] = *(const uint4*)&BT[(size_t)(n0 + row) * Ktot + k0 + c8 * 8];
    }
    __syncthreads();
#pragma unroll
    for (int ks = 0; ks < 64; ks += 32){
      bf16x8 a  = *(const bf16x8*)&As[wm * 16 + mr][ks + q * 8];
      bf16x8 b0 = *(const bf16x8*)&Bs[wn * 32 + mr][ks + q * 8];
      bf16x8 b1 = *(const bf16x8*)&Bs[wn * 32 + 16 + mr][ks + q * 8];
      acc[0] = __builtin_amdgcn_mfma_f32_16x16x32_bf16(a, b0, acc[0], 0, 0, 0);
      acc[1] = __builtin_amdgcn_mfma_f32_16x16x32_bf16(a, b1, acc[1], 0, 0, 0);
    }
    __syncthreads();
  }
#pragma unroll
  for (int nt = 0; nt < 2; ++nt){
    int col = n0 + wn * 32 + nt * 16 + mr;
#pragma unroll
    for (int r = 0; r < 4; ++r){
      int row = m0 + wm * 16 + q * 4 + r;
      atomicAdd(&accF[(size_t)row * 1024 + col], acc[nt][r]);
    }
  }
  // ---- decoupled finisher: last split-K block per tile applies the epilogue
  __threadfence();
  __shared__ int is_last;
  int cidx = blockIdx.x * gridDim.y + blockIdx.y;
  if (tid == 0){
    int old = atomicAdd(&ctr[cidx], 1);
    is_last = (old == S - 1);
  }
  __syncthreads();
  if (!is_last) return;
  __threadfence();   // acquire: make other blocks' accF atomics visible
  for (int e = tid; e < 32 * 64; e += 256){
    int rr = e >> 6, cc = e & 63;
    size_t idx = (size_t)(m0 + rr) * 1024 + (n0 + cc);
    float ssum = accF[idx];
    accF[idx] = 0.f;                    // re-zero for next GEMM dispatch
    if (mode == 1){
      outH[idx] = f2bf(tanhf(ssum));
    } else if (mode == 2){
      outH[idx] = f2bf(ssum);
    } else {
      float g = 1.f / (1.f + expf(-(ssum + bias[(int)(idx & 1023)])));
      float uo = uin[idx];
      float ct = bf2f(ctxtin[idx]);
      float un = ct + g * (uo - ct);
      outF[idx] = un;
      outH[idx] = f2bf(un);
    }
  }
  if (tid == 0) ctr[cidx] = 0;          // reset counter for next GEMM dispatch
}

// ---------------- ctxt via MFMA (32x64 tiles, grid 768)
__global__ __launch_bounds__(256)
void ctxt_mfma(const u16* __restrict__ Pbf, const u16* __restrict__ PTbf,
               const u16* __restrict__ uT, const float* __restrict__ rowsum,
               const float* __restrict__ colsum, u16* __restrict__ c1,
               u16* __restrict__ c2){
  __shared__ u16 As[32][72];
  __shared__ u16 Bs[64][72];
  int z = blockIdx.z, b = z >> 1, which = z & 1;
  const u16* A = (which ? PTbf : Pbf) + (size_t)b * K_ * K_;
  const u16* BT = uT + (size_t)b * D_ * K_;
  const float* sums = (which ? colsum : rowsum) + b * K_;
  u16* out = which ? c2 : c1;
  int tid = threadIdx.x;
  int m0 = blockIdx.x * 32, n0 = blockIdx.y * 64;
  int wave = tid >> 6, lane = tid & 63;
  int wm = wave >> 1, wn = wave & 1;
  int q = lane >> 4, mr = lane & 15;
  f32x4 acc[2] = {{0.f,0.f,0.f,0.f},{0.f,0.f,0.f,0.f}};
  for (int k0 = 0; k0 < K_; k0 += 64){
    {
      int row = tid >> 3, c8 = tid & 7;
      *(uint4*)&As[row][c8 * 8] = *(const uint4*)&A[(size_t)(m0 + row) * K_ + k0 + c8 * 8];
    }
    for (int c = tid; c < 512; c += 256){
      int row = c >> 3, c8 = c & 7;
      *(uint4*)&Bs[row][c8 * 8] = *(const uint4*)&BT[(size_t)(n0 + row) * K_ + k0 + c8 * 8];
    }
    __syncthreads();
#pragma unroll
    for (int ks = 0; ks < 64; ks += 32){
      bf16x8 a  = *(const bf16x8*)&As[wm * 16 + mr][ks + q * 8];
      bf16x8 b0 = *(const bf16x8*)&Bs[wn * 32 + mr][ks + q * 8];
      bf16x8 b1 = *(const bf16x8*)&Bs[wn * 32 + 16 + mr][ks + q * 8];
      acc[0] = __builtin_amdgcn_mfma_f32_16x16x32_bf16(a, b0, acc[0], 0, 0, 0);
      acc[1] = __builtin_amdgcn_mfma_f32_16x16x32_bf16(a, b1, acc[1], 0, 0, 0);
    }
    __syncthreads();
  }
#pragma unroll
  for (int nt = 0; nt < 2; ++nt){
    int col = n0 + wn * 32 + nt * 16 + mr;
#pragma unroll
    for (int r = 0; r < 4; ++r){
      int row = m0 + wm * 16 + q * 4 + r;
      float w = 1.f / (sums[row] + 1e-7f);
      out[((size_t)(b * K_ + row)) * D_ + col] = f2bf(acc[nt][r] * w);
    }
  }
}

// ---------------- scorer (MFMA, wave-autonomous; reg-prefetch build, WoT table)
// Fused probs: p = sigmoid(max_l score)*mask -> pbf, pTbf, rowsum, colsum (when wprobs)
// lr layout: stride 320, l at [0,150), r at [160,310), zeros [310,320)
__global__ __launch_bounds__(256)
void scorer_kernel(const float* __restrict__ lr, const float* __restrict__ dWg,
                   const u16* __restrict__ woT, const float* __restrict__ bo,
                   const int* __restrict__ span_begin, const int* __restrict__ span_end,
                   float* __restrict__ scores, int accumulate,
                   const float* __restrict__ mask, u16* __restrict__ pbf,
                   u16* __restrict__ pTbf, float* __restrict__ rowsum,
                   float* __restrict__ colsum, int wprobs){
  __shared__ float ldw[NB_ * LDW_S];
  __shared__ u16 h_s[4][16][168];
  int i = blockIdx.x, jblk = blockIdx.y, b = blockIdx.z;
  int tid = threadIdx.x;
  int row_i = b * K_ + i;
  int se = span_end[row_i];
  // stage ldw = l_i + dW (zero pad t>=150), block-cooperative
  for (int e = tid; e < NB_ * LDW_S; e += 256){
    int nb = e / LDW_S, t = e - nb * LDW_S;
    ldw[e] = (t < H_) ? (lr[(size_t)row_i * 320 + t] + dWg[nb * H_ + t]) : 0.f;
  }
  int wave = tid >> 6, lane = tid & 63;
  int q = lane >> 4, mr = lane & 15;
  // Wo^T fragments from precomputed bf16 table: 5 x dwordx4 loads
  bf16x8 wo_frag[5];
#pragma unroll
  for (int kk = 0; kk < 5; ++kk)
    wo_frag[kk] = *(const bf16x8*)&woT[mr * 160 + kk * 32 + q * 8];
  // zero this wave's h tail cols [150,160)
  for (int e = lane; e < 16 * 5; e += 64){
    int row = e / 5, w5 = e - row * 5;
    *(unsigned*)&h_s[wave][row][150 + w5 * 2] = 0u;
  }
  float bov = (mr < L_) ? bo[mr] : 0.f;
  int rt = lane >> 2, tq = lane & 3;   // build mapping: 4 lanes per row
  float rsum = 0.f;
  __syncthreads();
#pragma unroll
  for (int p = 0; p < 2; ++p){
    int j0w = jblk * 128 + wave * 32 + p * 16;
    // build h bf16 for this wave's 16 rows: prefetch r row into registers (19 batched
    // loads, one waitcnt), then compute. pp==75 reads zeros -> writes zeros (tail).
    {
      int j = j0w + rt;
      int bk = bucketf(span_begin[b * K_ + j] - se);
      const float2* rr = (const float2*)(lr + (size_t)(b * K_ + j) * 320 + 160);
      const float2* lw = (const float2*)(ldw + bk * LDW_S);
      u16* hrow = &h_s[wave][rt][0];
      int pp0 = tq * 19;
      float2 rbuf[19];
#pragma unroll
      for (int s = 0; s < 19; ++s) rbuf[s] = rr[pp0 + s];
#pragma unroll
      for (int s = 0; s < 19; ++s){
        int pp = pp0 + s;
        float2 lv = lw[pp];
        __bf16 h0 = (__bf16)fmaxf(lv.x + rbuf[s].x, 0.f);
        __bf16 h1 = (__bf16)fmaxf(lv.y + rbuf[s].y, 0.f);
        unsigned pk = (unsigned)__builtin_bit_cast(u16, h0) |
                      ((unsigned)__builtin_bit_cast(u16, h1) << 16);
        *(unsigned*)&hrow[pp * 2] = pk;
      }
    }
    // MFMA: 16 j rows x 16 l cols (12 valid), K=160 (intra-wave LDS dep only)
    f32x4 acc = {0.f, 0.f, 0.f, 0.f};
#pragma unroll
    for (int kk = 0; kk < 5; ++kk){
      bf16x8 a = *(const bf16x8*)&h_s[wave][mr][kk * 32 + q * 8];
      acc = __builtin_amdgcn_mfma_f32_16x16x32_bf16(a, wo_frag[kk], acc, 0, 0, 0);
    }
#pragma unroll
    for (int r = 0; r < 4; ++r){
      int j = j0w + q * 4 + r;
      float v = -3.0e38f;
      if (mr < L_){
        size_t addr = ((size_t)row_i * K_ + j) * L_ + mr;
        v = acc[r] + bov;
        if (accumulate) v += scores[addr];
        scores[addr] = v;
      }
      // masked cross-lane max over the 16-lane label group
      float mx = v;
      mx = fmaxf(mx, __shfl_xor(mx, 1, 16));
      mx = fmaxf(mx, __shfl_xor(mx, 2, 16));
      mx = fmaxf(mx, __shfl_xor(mx, 4, 16));
      mx = fmaxf(mx, __shfl_xor(mx, 8, 16));
      if (wprobs && mr == 0){
        size_t pb = (size_t)row_i * K_ + j;
        float pp = mask[pb] / (1.f + expf(-mx));
        u16 ph = f2bf(pp);
        pbf[pb] = ph;
        pTbf[((size_t)b * K_ + j) * K_ + i] = ph;
        atomicAdd(&colsum[b * K_ + j], pp);
        rsum += pp;
      }
    }
  }
  if (wprobs && mr == 0) atomicAdd(&rowsum[row_i], rsum);
}

// ---------------- float4 copy
__global__ void copy_f4(const float4* __restrict__ src, float4* __restrict__ dst, int n){
  int g = blockIdx.x * 256 + threadIdx.x;
  if (g < n) dst[g] = src[g];
}

// ---------------- overwrite_spans scatter (numpy last-wins for duplicate indices)
__global__ void scatter_kernel(const float* __restrict__ u, const int* __restrict__ prune,
                               const int* __restrict__ span_len, float* __restrict__ outA){
  int blk = blockIdx.x;
  int b = blk / K_, k = blk - b * K_;
  int idx = prune[b * K_ + k];
  bool valid = k < span_len[b];
  bool winner = (k == K_ - 1) || (prune[b * K_ + k + 1] != idx);
  if (!(valid && winner)) return;
  const float4* src = (const float4*)(u + ((size_t)b * K_ + k) * D_);
  float4* dst = (float4*)(outA + ((size_t)b * N_ + idx) * D_);
  for (int t = threadIdx.x; t < D_ / 4; t += blockDim.x) dst[t] = src[t];
}

extern "C" void kernel_launch(void* const* d_in, const int* in_sizes, int n_in,
                              void* d_out, int out_size, void* d_ws, size_t ws_size,
                              hipStream_t stream){
  const float* span_vecs = (const float*)d_in[0];
  const float* all_span  = (const float*)d_in[1];
  const int*   span_begin = (const int*)d_in[2];
  const int*   span_end   = (const int*)d_in[3];
  const float* mask       = (const float*)d_in[4];
  const int*   prune      = (const int*)d_in[5];
  const int*   span_len   = (const int*)d_in[6];
  const float* Wl  = (const float*)d_in[8];
  const float* bl  = (const float*)d_in[9];
  const float* Wr  = (const float*)d_in[10];
  const float* br  = (const float*)d_in[11];
  const float* dist_emb = (const float*)d_in[12];
  const float* Wd  = (const float*)d_in[13];
  const float* bd  = (const float*)d_in[14];
  const float* Wo  = (const float*)d_in[15];
  const float* bo  = (const float*)d_in[16];
  const float* Wff1 = (const float*)d_in[17];
  const float* Wff2 = (const float*)d_in[18];
  const float* Wg  = (const float*)d_in[19];
  const float* bg  = (const float*)d_in[20];

  float* outA = (float*)d_out;                       // (B,N,D)
  float* outU = outA + (size_t)B_ * N_ * D_;         // (B,K,D)
  float* outS = outU + (size_t)B_ * K_ * D_;         // (B,K,K,L)

  char* base = (char*)d_ws;
  size_t off = 0;
  auto alloc = [&](size_t bytes) -> void* {
    void* p = base + off;
    off = (off + bytes + 255) & ~((size_t)255);
    return p;
  };
  u16* WlrT  = (u16*)alloc((size_t)320 * 1024 * sizeof(u16));
  u16* Wff1T = (u16*)alloc((size_t)1024 * 3072 * sizeof(u16));
  u16* Wff2T = (u16*)alloc((size_t)1024 * 1024 * sizeof(u16));
  u16* WgT   = (u16*)alloc((size_t)1024 * 2048 * sizeof(u16));
  float* dWg = (float*)alloc(NB_ * H_ * sizeof(float));
  float* blr = (float*)alloc(300 * sizeof(float));
  u16* woT   = (u16*)alloc((size_t)16 * 160 * sizeof(u16));
  int* gctr  = (int*)alloc(384 * sizeof(int));
  float* lr  = (float*)alloc((size_t)B_ * K_ * 320 * sizeof(float));
  u16* pbf   = (u16*)alloc((size_t)B_ * K_ * K_ * sizeof(u16));
  u16* pTbf  = (u16*)alloc((size_t)B_ * K_ * K_ * sizeof(u16));
  u16* uTbf  = (u16*)alloc((size_t)B_ * D_ * K_ * sizeof(u16));
  float* rowsum = (float*)alloc((size_t)2 * B_ * K_ * sizeof(float));
  float* colsum = rowsum + B_ * K_;
  u16* ubf0 = (u16*)alloc((size_t)B_ * K_ * D_ * sizeof(u16));
  u16* ubf1 = (u16*)alloc((size_t)B_ * K_ * D_ * sizeof(u16));
  u16* c1bf = (u16*)alloc((size_t)B_ * K_ * D_ * sizeof(u16));
  u16* c2bf = (u16*)alloc((size_t)B_ * K_ * D_ * sizeof(u16));
  u16* tbf  = (u16*)alloc((size_t)B_ * K_ * D_ * sizeof(u16));
  u16* ctxtbf = (u16*)alloc((size_t)B_ * K_ * D_ * sizeof(u16));
  float* uA = (float*)alloc((size_t)B_ * K_ * D_ * sizeof(float));
  float* accF = (float*)alloc((size_t)B_ * K_ * D_ * sizeof(float));  // split-K fp32 accum
  u16* ubf[2] = {ubf0, ubf1};
  (void)ws_size; (void)in_sizes; (void)n_in; (void)out_size;

  dim3 tb(32, 8);
  (void)hipMemsetAsync(WlrT, 0, (size_t)320 * 1024 * sizeof(u16), stream);  // zero pad rows
  transpose_f2bf<<<dim3(5, 32), tb, 0, stream>>>(Wl, WlrT, 1024, 150, 1024);
  transpose_f2bf<<<dim3(5, 32), tb, 0, stream>>>(Wr, WlrT + (size_t)160 * 1024, 1024, 150, 1024);
  transpose_f2bf<<<dim3(32, 96), tb, 0, stream>>>(Wff1, Wff1T, 3072, 1024, 3072);
  transpose_f2bf<<<dim3(32, 32), tb, 0, stream>>>(Wff2, Wff2T, 1024, 1024, 1024);
  transpose_f2bf<<<dim3(32, 64), tb, 0, stream>>>(Wg, WgT, 2048, 1024, 2048);
  small_setup<<<1, 256, 0, stream>>>(dist_emb, Wd, bd, bl, br, Wo, dWg, blr, woT);
  cvt_f32_bf16<<<768, 256, 0, stream>>>(span_vecs, ubf[0], B_ * K_ * D_);
  (void)hipMemsetAsync(accF, 0, (size_t)B_ * K_ * D_ * sizeof(float), stream);  // fused epis self-zero
  (void)hipMemsetAsync(gctr, 0, 384 * sizeof(int), stream);                     // finishers self-reset

  // lr = u0 @ [Wl|0|Wr|0] + bias   (split-K=8, 32x64 tiles, 960 blocks, atomic into bias-filled lr)
  init_lr<<<960, 256, 0, stream>>>(blr, lr);
  gemm_part_atomic32<<<dim3(24, 5, 8), 256, 0, stream>>>(ubf[0], nullptr, nullptr, WlrT,
                                                         1024, 128, lr, 320);
  (void)hipMemsetAsync(rowsum, 0, (size_t)2 * B_ * K_ * sizeof(float), stream);
  scorer_kernel<<<dim3(K_, 3, B_), 256, 0, stream>>>(lr, dWg, woT, bo, span_begin, span_end,
                                                     outS, 0, mask, pbf, pTbf, rowsum, colsum, 1);

  const float* ucurF = span_vecs;
  int cb = 0;
  float* unexts[2] = {uA, outU};   // it=1 writes u directly into d_out
  for (int it = 0; it < 2; ++it){
    transpose_bf<<<dim3(32, 12, B_), tb, 0, stream>>>(ubf[cb], uTbf);
    ctxt_mfma<<<dim3(12, 16, 2 * B_), 256, 0, stream>>>(pbf, pTbf, uTbf, rowsum, colsum,
                                                        c1bf, c2bf);
    // tbf = tanh(cat(u,c1,c2) @ Wff1)   K=3072, split-K=4, fused epilogue
    gemm_fused<<<dim3(24, 16, 4), 256, 0, stream>>>(ubf[cb], c1bf, c2bf, Wff1T,
                                                    3072, 768, accF, gctr, 4, 1,
                                                    nullptr, nullptr, tbf, nullptr, nullptr);
    // ctxt = tbf @ Wff2                 K=1024, split-K=4, fused epilogue
    gemm_fused<<<dim3(24, 16, 4), 256, 0, stream>>>(tbf, nullptr, nullptr, Wff2T,
                                                    1024, 256, accF, gctr, 4, 2,
                                                    nullptr, nullptr, ctxtbf, nullptr, nullptr);
    // gate: g = sigmoid(cat(u,ctxt) @ Wg + bg); un = g*u + (1-g)*ctxt   K=2048, fused epilogue
    float* unext = unexts[it];
    gemm_fused<<<dim3(24, 16, 4), 256, 0, stream>>>(ubf[cb], ctxtbf, nullptr, WgT,
                                                    2048, 512, accF, gctr, 4, 3,
                                                    bg, unext, ubf[1 - cb], ucurF, ctxtbf);
    cb = 1 - cb;
    ucurF = unext;
    // lr for next scorer               K=1024, split-K=8
    init_lr<<<960, 256, 0, stream>>>(blr, lr);
    gemm_part_atomic32<<<dim3(24, 5, 8), 256, 0, stream>>>(ubf[cb], nullptr, nullptr, WlrT,
                                                           1024, 128, lr, 320);
    if (it == 0){
      (void)hipMemsetAsync(rowsum, 0, (size_t)2 * B_ * K_ * sizeof(float), stream);
      scorer_kernel<<<dim3(K_, 3, B_), 256, 0, stream>>>(lr, dWg, woT, bo, span_begin, span_end,
                                                         outS, 1, mask, pbf, pTbf, rowsum, colsum, 1);
    } else {
      scorer_kernel<<<dim3(K_, 3, B_), 256, 0, stream>>>(lr, dWg, woT, bo, span_begin, span_end,
                                                         outS, 1, mask, pbf, pTbf, rowsum, colsum, 0);
    }
  }

  copy_f4<<<8192, 256, 0, stream>>>((const float4*)all_span, (float4*)outA, (B_ * N_ * D_) / 4);
  // ucurF == outU after it=1 — no final u copy needed
  scatter_kernel<<<B_ * K_, 256, 0, stream>>>(ucurF, prune, span_len, outA);
}

// Round 12
// 609.169 us; speedup vs baseline: 2.1864x; 2.1864x over previous
//
#include <hip/hip_runtime.h>
#include <cmath>

#define B_ 2
#define K_ 384
#define N_ 4096
#define D_ 1024
#define H_ 150
#define L_ 12
#define NB_ 10
#define LDW_S 164   // padded ldw row stride (164 % 32 = 4 dwords -> buckets on distinct banks)

typedef unsigned short u16;
typedef __bf16 bf16x8 __attribute__((ext_vector_type(8)));
typedef float f32x4 __attribute__((ext_vector_type(4)));

__device__ __forceinline__ u16 f2bf(float f){
  unsigned u = __builtin_bit_cast(unsigned, f);
  unsigned r = (u + 0x7FFFu + ((u >> 16) & 1u)) >> 16;
  return (u16)r;
}
__device__ __forceinline__ float bf2f(u16 h){
  unsigned u = ((unsigned)h) << 16;
  return __builtin_bit_cast(float, u);
}
__device__ __forceinline__ int bucketf(int d){
  int da = d < 0 ? -d : d;
  if (da <= 4) return da;
  int lg = 31 - __clz(da);
  int v = lg + 3;
  return v > NB_ - 1 ? NB_ - 1 : v;
}

// ---------------- transpose fp32 (Kd x Nd) -> bf16 (Nd x Kd), out row stride = ostride
__global__ void transpose_f2bf(const float* __restrict__ in, u16* __restrict__ out,
                               int Kd, int Nd, int ostride){
  __shared__ float t[32][33];
  int bx = blockIdx.x * 32, by = blockIdx.y * 32;
  int tx = threadIdx.x, ty = threadIdx.y;
  for (int i = 0; i < 32; i += 8){
    int k = by + ty + i, n = bx + tx;
    t[ty + i][tx] = (k < Kd && n < Nd) ? in[(size_t)k * Nd + n] : 0.f;
  }
  __syncthreads();
  for (int i = 0; i < 32; i += 8){
    int n = bx + ty + i, k = by + tx;
    if (n < Nd && k < Kd) out[(size_t)n * ostride + k] = f2bf(t[tx][ty + i]);
  }
}

// ---------------- transpose bf16 (K_ x D_) -> (D_ x K_) per batch
__global__ void transpose_bf(const u16* __restrict__ in, u16* __restrict__ out){
  __shared__ u16 t[32][34];
  int b = blockIdx.z;
  const u16* I = in + (size_t)b * K_ * D_;
  u16* O = out + (size_t)b * D_ * K_;
  int bx = blockIdx.x * 32, by = blockIdx.y * 32;  // bx: d, by: k
  int tx = threadIdx.x, ty = threadIdx.y;
  for (int i = 0; i < 32; i += 8) t[ty + i][tx] = I[(size_t)(by + ty + i) * D_ + bx + tx];
  __syncthreads();
  for (int i = 0; i < 32; i += 8) O[(size_t)(bx + ty + i) * K_ + by + tx] = t[tx][ty + i];
}

// ---------------- small setup: dW = dist_emb @ Wd + bd ; blr = [bl|br] ; WoT bf16 [16][160]
__global__ void small_setup(const float* __restrict__ dist_emb, const float* __restrict__ Wd,
                            const float* __restrict__ bd, const float* __restrict__ bl,
                            const float* __restrict__ br, const float* __restrict__ Wo,
                            float* __restrict__ dWg, float* __restrict__ blr,
                            u16* __restrict__ woT){
  int tid = threadIdx.x;
  for (int idx = tid; idx < NB_ * H_; idx += 256){
    int nb = idx / H_, h = idx - nb * H_;
    float s = bd[h];
    for (int dd = 0; dd < 20; ++dd) s += dist_emb[nb * 20 + dd] * Wd[dd * H_ + h];
    dWg[idx] = s;
  }
  for (int idx = tid; idx < H_; idx += 256){
    blr[idx] = bl[idx];
    blr[H_ + idx] = br[idx];
  }
  for (int idx = tid; idx < 16 * 160; idx += 256){
    int l = idx / 160, t = idx - l * 160;
    float w = (l < L_ && t < H_) ? Wo[t * L_ + l] : 0.f;
    woT[idx] = f2bf(w);
  }
}

// ---------------- fp32 -> bf16 elementwise (n divisible by 4)
__global__ void cvt_f32_bf16(const float* __restrict__ in, u16* __restrict__ out, int n){
  int idx = (blockIdx.x * 256 + threadIdx.x) * 4;
  if (idx < n){
    float4 v = *(const float4*)(in + idx);
    ushort4 o;
    o.x = f2bf(v.x); o.y = f2bf(v.y); o.z = f2bf(v.z); o.w = f2bf(v.w);
    *(ushort4*)(out + idx) = o;
  }
}

// ---------------- init lr (stride 320): l bias [0,150), r bias [160,310), zeros elsewhere
__global__ void init_lr(const float* __restrict__ blr, float* __restrict__ lr){
  int idx = blockIdx.x * 256 + threadIdx.x;
  if (idx >= (B_ * K_) * 320) return;
  int col = idx % 320;
  float v = 0.f;
  if (col < 150) v = blr[col];
  else if (col >= 160 && col < 310) v = blr[150 + (col - 160)];
  lr[idx] = v;
}

// ---------------- bf16 MFMA GEMM (32x64 tile), split-K atomic; dims must divide exactly
__global__ __launch_bounds__(256)
void gemm_part_atomic32(const u16* __restrict__ A0, const u16* __restrict__ A1,
                        const u16* __restrict__ A2, const u16* __restrict__ BT,
                        int Ktot, int klen, float* __restrict__ Out, int ldo){
  __shared__ u16 As[32][72];
  __shared__ u16 Bs[64][72];
  int tid = threadIdx.x;
  int m0 = blockIdx.x * 32, n0 = blockIdx.y * 64;
  int s = blockIdx.z;
  int kbeg = s * klen, kend = kbeg + klen;
  int wave = tid >> 6, lane = tid & 63;
  int wm = wave >> 1, wn = wave & 1;
  int q = lane >> 4, mr = lane & 15;
  f32x4 acc[2] = {{0.f,0.f,0.f,0.f},{0.f,0.f,0.f,0.f}};
  const u16* Achunks[3] = {A0, A1, A2};
  for (int k0 = kbeg; k0 < kend; k0 += 64){
    const u16* Ap = Achunks[k0 >> 10] + (k0 & 1023);
    {
      int row = tid >> 3, c8 = tid & 7;
      *(uint4*)&As[row][c8 * 8] = *(const uint4*)&Ap[(size_t)(m0 + row) * 1024 + c8 * 8];
    }
    for (int c = tid; c < 512; c += 256){
      int row = c >> 3, c8 = c & 7;
      *(uint4*)&Bs[row][c8 * 8] = *(const uint4*)&BT[(size_t)(n0 + row) * Ktot + k0 + c8 * 8];
    }
    __syncthreads();
#pragma unroll
    for (int ks = 0; ks < 64; ks += 32){
      bf16x8 a  = *(const bf16x8*)&As[wm * 16 + mr][ks + q * 8];
      bf16x8 b0 = *(const bf16x8*)&Bs[wn * 32 + mr][ks + q * 8];
      bf16x8 b1 = *(const bf16x8*)&Bs[wn * 32 + 16 + mr][ks + q * 8];
      acc[0] = __builtin_amdgcn_mfma_f32_16x16x32_bf16(a, b0, acc[0], 0, 0, 0);
      acc[1] = __builtin_amdgcn_mfma_f32_16x16x32_bf16(a, b1, acc[1], 0, 0, 0);
    }
    __syncthreads();
  }
#pragma unroll
  for (int nt = 0; nt < 2; ++nt){
    int col = n0 + wn * 32 + nt * 16 + mr;
#pragma unroll
    for (int r = 0; r < 4; ++r){
      int row = m0 + wm * 16 + q * 4 + r;
      atomicAdd(&Out[(size_t)row * ldo + col], acc[nt][r]);
    }
  }
}

// ---------------- epilogue over fp32 accum (ld = 1024); re-zeros accF for next use
__global__ __launch_bounds__(256)
void gemm_epi(float* __restrict__ accF, int n,
              const float* __restrict__ bias, int mode,
              float* __restrict__ outF, u16* __restrict__ outH,
              const float* __restrict__ uin, const u16* __restrict__ ctxtin){
  int idx = blockIdx.x * 256 + threadIdx.x;
  if (idx >= n) return;
  float ssum = accF[idx];
  accF[idx] = 0.f;                       // self-zero: next split-K GEMM needs zeroed accum
  if (mode == 1){
    outH[idx] = f2bf(tanhf(ssum));
  } else if (mode == 2){
    outH[idx] = f2bf(ssum);
  } else {
    int col = idx & 1023;
    float g = 1.f / (1.f + expf(-(ssum + bias[col])));
    float uo = uin[idx];
    float ct = bf2f(ctxtin[idx]);
    float un = ct + g * (uo - ct);
    outF[idx] = un;
    outH[idx] = f2bf(un);
  }
}

// ---------------- ctxt via MFMA (32x64 tiles, grid 768)
__global__ __launch_bounds__(256)
void ctxt_mfma(const u16* __restrict__ Pbf, const u16* __restrict__ PTbf,
               const u16* __restrict__ uT, const float* __restrict__ rowsum,
               const float* __restrict__ colsum, u16* __restrict__ c1,
               u16* __restrict__ c2){
  __shared__ u16 As[32][72];
  __shared__ u16 Bs[64][72];
  int z = blockIdx.z, b = z >> 1, which = z & 1;
  const u16* A = (which ? PTbf : Pbf) + (size_t)b * K_ * K_;
  const u16* BT = uT + (size_t)b * D_ * K_;
  const float* sums = (which ? colsum : rowsum) + b * K_;
  u16* out = which ? c2 : c1;
  int tid = threadIdx.x;
  int m0 = blockIdx.x * 32, n0 = blockIdx.y * 64;
  int wave = tid >> 6, lane = tid & 63;
  int wm = wave >> 1, wn = wave & 1;
  int q = lane >> 4, mr = lane & 15;
  f32x4 acc[2] = {{0.f,0.f,0.f,0.f},{0.f,0.f,0.f,0.f}};
  for (int k0 = 0; k0 < K_; k0 += 64){
    {
      int row = tid >> 3, c8 = tid & 7;
      *(uint4*)&As[row][c8 * 8] = *(const uint4*)&A[(size_t)(m0 + row) * K_ + k0 + c8 * 8];
    }
    for (int c = tid; c < 512; c += 256){
      int row = c >> 3, c8 = c & 7;
      *(uint4*)&Bs[row][c8 * 8] = *(const uint4*)&BT[(size_t)(n0 + row) * K_ + k0 + c8 * 8];
    }
    __syncthreads();
#pragma unroll
    for (int ks = 0; ks < 64; ks += 32){
      bf16x8 a  = *(const bf16x8*)&As[wm * 16 + mr][ks + q * 8];
      bf16x8 b0 = *(const bf16x8*)&Bs[wn * 32 + mr][ks + q * 8];
      bf16x8 b1 = *(const bf16x8*)&Bs[wn * 32 + 16 + mr][ks + q * 8];
      acc[0] = __builtin_amdgcn_mfma_f32_16x16x32_bf16(a, b0, acc[0], 0, 0, 0);
      acc[1] = __builtin_amdgcn_mfma_f32_16x16x32_bf16(a, b1, acc[1], 0, 0, 0);
    }
    __syncthreads();
  }
#pragma unroll
  for (int nt = 0; nt < 2; ++nt){
    int col = n0 + wn * 32 + nt * 16 + mr;
#pragma unroll
    for (int r = 0; r < 4; ++r){
      int row = m0 + wm * 16 + q * 4 + r;
      float w = 1.f / (sums[row] + 1e-7f);
      out[((size_t)(b * K_ + row)) * D_ + col] = f2bf(acc[nt][r] * w);
    }
  }
}

// ---------------- scorer (MFMA, wave-autonomous; reg-prefetch build, WoT table)
// Fused probs: p = sigmoid(max_l score)*mask -> pbf, pTbf, rowsum, colsum (when wprobs)
// lr layout: stride 320, l at [0,150), r at [160,310), zeros [310,320)
__global__ __launch_bounds__(256)
void scorer_kernel(const float* __restrict__ lr, const float* __restrict__ dWg,
                   const u16* __restrict__ woT, const float* __restrict__ bo,
                   const int* __restrict__ span_begin, const int* __restrict__ span_end,
                   float* __restrict__ scores, int accumulate,
                   const float* __restrict__ mask, u16* __restrict__ pbf,
                   u16* __restrict__ pTbf, float* __restrict__ rowsum,
                   float* __restrict__ colsum, int wprobs){
  __shared__ float ldw[NB_ * LDW_S];
  __shared__ u16 h_s[4][16][168];
  int i = blockIdx.x, jblk = blockIdx.y, b = blockIdx.z;
  int tid = threadIdx.x;
  int row_i = b * K_ + i;
  int se = span_end[row_i];
  // stage ldw = l_i + dW (zero pad t>=150), block-cooperative
  for (int e = tid; e < NB_ * LDW_S; e += 256){
    int nb = e / LDW_S, t = e - nb * LDW_S;
    ldw[e] = (t < H_) ? (lr[(size_t)row_i * 320 + t] + dWg[nb * H_ + t]) : 0.f;
  }
  int wave = tid >> 6, lane = tid & 63;
  int q = lane >> 4, mr = lane & 15;
  // Wo^T fragments from precomputed bf16 table: 5 x dwordx4 loads
  bf16x8 wo_frag[5];
#pragma unroll
  for (int kk = 0; kk < 5; ++kk)
    wo_frag[kk] = *(const bf16x8*)&woT[mr * 160 + kk * 32 + q * 8];
  // zero this wave's h tail cols [150,160)
  for (int e = lane; e < 16 * 5; e += 64){
    int row = e / 5, w5 = e - row * 5;
    *(unsigned*)&h_s[wave][row][150 + w5 * 2] = 0u;
  }
  float bov = (mr < L_) ? bo[mr] : 0.f;
  int rt = lane >> 2, tq = lane & 3;   // build mapping: 4 lanes per row
  float rsum = 0.f;
  __syncthreads();
#pragma unroll
  for (int p = 0; p < 2; ++p){
    int j0w = jblk * 128 + wave * 32 + p * 16;
    // build h bf16 for this wave's 16 rows: prefetch r row into registers (19 batched
    // loads, one waitcnt), then compute. pp==75 reads zeros -> writes zeros (tail).
    {
      int j = j0w + rt;
      int bk = bucketf(span_begin[b * K_ + j] - se);
      const float2* rr = (const float2*)(lr + (size_t)(b * K_ + j) * 320 + 160);
      const float2* lw = (const float2*)(ldw + bk * LDW_S);
      u16* hrow = &h_s[wave][rt][0];
      int pp0 = tq * 19;
      float2 rbuf[19];
#pragma unroll
      for (int s = 0; s < 19; ++s) rbuf[s] = rr[pp0 + s];
#pragma unroll
      for (int s = 0; s < 19; ++s){
        int pp = pp0 + s;
        float2 lv = lw[pp];
        __bf16 h0 = (__bf16)fmaxf(lv.x + rbuf[s].x, 0.f);
        __bf16 h1 = (__bf16)fmaxf(lv.y + rbuf[s].y, 0.f);
        unsigned pk = (unsigned)__builtin_bit_cast(u16, h0) |
                      ((unsigned)__builtin_bit_cast(u16, h1) << 16);
        *(unsigned*)&hrow[pp * 2] = pk;
      }
    }
    // MFMA: 16 j rows x 16 l cols (12 valid), K=160 (intra-wave LDS dep only)
    f32x4 acc = {0.f, 0.f, 0.f, 0.f};
#pragma unroll
    for (int kk = 0; kk < 5; ++kk){
      bf16x8 a = *(const bf16x8*)&h_s[wave][mr][kk * 32 + q * 8];
      acc = __builtin_amdgcn_mfma_f32_16x16x32_bf16(a, wo_frag[kk], acc, 0, 0, 0);
    }
#pragma unroll
    for (int r = 0; r < 4; ++r){
      int j = j0w + q * 4 + r;
      float v = -3.0e38f;
      if (mr < L_){
        size_t addr = ((size_t)row_i * K_ + j) * L_ + mr;
        v = acc[r] + bov;
        if (accumulate) v += scores[addr];
        scores[addr] = v;
      }
      // masked cross-lane max over the 16-lane label group
      float mx = v;
      mx = fmaxf(mx, __shfl_xor(mx, 1, 16));
      mx = fmaxf(mx, __shfl_xor(mx, 2, 16));
      mx = fmaxf(mx, __shfl_xor(mx, 4, 16));
      mx = fmaxf(mx, __shfl_xor(mx, 8, 16));
      if (wprobs && mr == 0){
        size_t pb = (size_t)row_i * K_ + j;
        float pp = mask[pb] / (1.f + expf(-mx));
        u16 ph = f2bf(pp);
        pbf[pb] = ph;
        pTbf[((size_t)b * K_ + j) * K_ + i] = ph;
        atomicAdd(&colsum[b * K_ + j], pp);
        rsum += pp;
      }
    }
  }
  if (wprobs && mr == 0) atomicAdd(&rowsum[row_i], rsum);
}

// ---------------- float4 copy
__global__ void copy_f4(const float4* __restrict__ src, float4* __restrict__ dst, int n){
  int g = blockIdx.x * 256 + threadIdx.x;
  if (g < n) dst[g] = src[g];
}

// ---------------- overwrite_spans scatter (numpy last-wins for duplicate indices)
__global__ void scatter_kernel(const float* __restrict__ u, const int* __restrict__ prune,
                               const int* __restrict__ span_len, float* __restrict__ outA){
  int blk = blockIdx.x;
  int b = blk / K_, k = blk - b * K_;
  int idx = prune[b * K_ + k];
  bool valid = k < span_len[b];
  bool winner = (k == K_ - 1) || (prune[b * K_ + k + 1] != idx);
  if (!(valid && winner)) return;
  const float4* src = (const float4*)(u + ((size_t)b * K_ + k) * D_);
  float4* dst = (float4*)(outA + ((size_t)b * N_ + idx) * D_);
  for (int t = threadIdx.x; t < D_ / 4; t += blockDim.x) dst[t] = src[t];
}

extern "C" void kernel_launch(void* const* d_in, const int* in_sizes, int n_in,
                              void* d_out, int out_size, void* d_ws, size_t ws_size,
                              hipStream_t stream){
  const float* span_vecs = (const float*)d_in[0];
  const float* all_span  = (const float*)d_in[1];
  const int*   span_begin = (const int*)d_in[2];
  const int*   span_end   = (const int*)d_in[3];
  const float* mask       = (const float*)d_in[4];
  const int*   prune      = (const int*)d_in[5];
  const int*   span_len   = (const int*)d_in[6];
  const float* Wl  = (const float*)d_in[8];
  const float* bl  = (const float*)d_in[9];
  const float* Wr  = (const float*)d_in[10];
  const float* br  = (const float*)d_in[11];
  const float* dist_emb = (const float*)d_in[12];
  const float* Wd  = (const float*)d_in[13];
  const float* bd  = (const float*)d_in[14];
  const float* Wo  = (const float*)d_in[15];
  const float* bo  = (const float*)d_in[16];
  const float* Wff1 = (const float*)d_in[17];
  const float* Wff2 = (const float*)d_in[18];
  const float* Wg  = (const float*)d_in[19];
  const float* bg  = (const float*)d_in[20];

  float* outA = (float*)d_out;                       // (B,N,D)
  float* outU = outA + (size_t)B_ * N_ * D_;         // (B,K,D)
  float* outS = outU + (size_t)B_ * K_ * D_;         // (B,K,K,L)

  char* base = (char*)d_ws;
  size_t off = 0;
  auto alloc = [&](size_t bytes) -> void* {
    void* p = base + off;
    off = (off + bytes + 255) & ~((size_t)255);
    return p;
  };
  u16* WlrT  = (u16*)alloc((size_t)320 * 1024 * sizeof(u16));
  u16* Wff1T = (u16*)alloc((size_t)1024 * 3072 * sizeof(u16));
  u16* Wff2T = (u16*)alloc((size_t)1024 * 1024 * sizeof(u16));
  u16* WgT   = (u16*)alloc((size_t)1024 * 2048 * sizeof(u16));
  float* dWg = (float*)alloc(NB_ * H_ * sizeof(float));
  float* blr = (float*)alloc(300 * sizeof(float));
  u16* woT   = (u16*)alloc((size_t)16 * 160 * sizeof(u16));
  float* lr  = (float*)alloc((size_t)B_ * K_ * 320 * sizeof(float));
  u16* pbf   = (u16*)alloc((size_t)B_ * K_ * K_ * sizeof(u16));
  u16* pTbf  = (u16*)alloc((size_t)B_ * K_ * K_ * sizeof(u16));
  u16* uTbf  = (u16*)alloc((size_t)B_ * D_ * K_ * sizeof(u16));
  float* rowsum = (float*)alloc((size_t)2 * B_ * K_ * sizeof(float));
  float* colsum = rowsum + B_ * K_;
  u16* ubf0 = (u16*)alloc((size_t)B_ * K_ * D_ * sizeof(u16));
  u16* ubf1 = (u16*)alloc((size_t)B_ * K_ * D_ * sizeof(u16));
  u16* c1bf = (u16*)alloc((size_t)B_ * K_ * D_ * sizeof(u16));
  u16* c2bf = (u16*)alloc((size_t)B_ * K_ * D_ * sizeof(u16));
  u16* tbf  = (u16*)alloc((size_t)B_ * K_ * D_ * sizeof(u16));
  u16* ctxtbf = (u16*)alloc((size_t)B_ * K_ * D_ * sizeof(u16));
  float* uA = (float*)alloc((size_t)B_ * K_ * D_ * sizeof(float));
  float* accF = (float*)alloc((size_t)B_ * K_ * D_ * sizeof(float));  // split-K fp32 accum
  u16* ubf[2] = {ubf0, ubf1};
  (void)ws_size; (void)in_sizes; (void)n_in; (void)out_size;

  dim3 tb(32, 8);
  (void)hipMemsetAsync(WlrT, 0, (size_t)320 * 1024 * sizeof(u16), stream);  // zero pad rows
  transpose_f2bf<<<dim3(5, 32), tb, 0, stream>>>(Wl, WlrT, 1024, 150, 1024);
  transpose_f2bf<<<dim3(5, 32), tb, 0, stream>>>(Wr, WlrT + (size_t)160 * 1024, 1024, 150, 1024);
  transpose_f2bf<<<dim3(32, 96), tb, 0, stream>>>(Wff1, Wff1T, 3072, 1024, 3072);
  transpose_f2bf<<<dim3(32, 32), tb, 0, stream>>>(Wff2, Wff2T, 1024, 1024, 1024);
  transpose_f2bf<<<dim3(32, 64), tb, 0, stream>>>(Wg, WgT, 2048, 1024, 2048);
  small_setup<<<1, 256, 0, stream>>>(dist_emb, Wd, bd, bl, br, Wo, dWg, blr, woT);
  cvt_f32_bf16<<<768, 256, 0, stream>>>(span_vecs, ubf[0], B_ * K_ * D_);
  (void)hipMemsetAsync(accF, 0, (size_t)B_ * K_ * D_ * sizeof(float), stream);  // once; epis self-zero

  // lr = u0 @ [Wl|0|Wr|0] + bias   (split-K=8, 32x64 tiles, 960 blocks, atomic into bias-filled lr)
  init_lr<<<960, 256, 0, stream>>>(blr, lr);
  gemm_part_atomic32<<<dim3(24, 5, 8), 256, 0, stream>>>(ubf[0], nullptr, nullptr, WlrT,
                                                         1024, 128, lr, 320);
  (void)hipMemsetAsync(rowsum, 0, (size_t)2 * B_ * K_ * sizeof(float), stream);
  scorer_kernel<<<dim3(K_, 3, B_), 256, 0, stream>>>(lr, dWg, woT, bo, span_begin, span_end,
                                                     outS, 0, mask, pbf, pTbf, rowsum, colsum, 1);

  const float* ucurF = span_vecs;
  int cb = 0;
  float* unexts[2] = {uA, outU};   // it=1 writes u directly into d_out
  for (int it = 0; it < 2; ++it){
    transpose_bf<<<dim3(32, 12, B_), tb, 0, stream>>>(ubf[cb], uTbf);
    ctxt_mfma<<<dim3(12, 16, 2 * B_), 256, 0, stream>>>(pbf, pTbf, uTbf, rowsum, colsum,
                                                        c1bf, c2bf);
    // tbf = tanh(cat(u,c1,c2) @ Wff1)   K=3072, split-K=4, 32x64 tiles (1536 blocks)
    gemm_part_atomic32<<<dim3(24, 16, 4), 256, 0, stream>>>(ubf[cb], c1bf, c2bf, Wff1T,
                                                            3072, 768, accF, 1024);
    gemm_epi<<<3072, 256, 0, stream>>>(accF, B_ * K_ * D_, nullptr, 1,
                                       nullptr, tbf, nullptr, nullptr);
    // ctxt = tbf @ Wff2                 K=1024, split-K=4
    gemm_part_atomic32<<<dim3(24, 16, 4), 256, 0, stream>>>(tbf, nullptr, nullptr, Wff2T,
                                                            1024, 256, accF, 1024);
    gemm_epi<<<3072, 256, 0, stream>>>(accF, B_ * K_ * D_, nullptr, 2,
                                       nullptr, ctxtbf, nullptr, nullptr);
    // gate: g = sigmoid(cat(u,ctxt) @ Wg + bg); un = g*u + (1-g)*ctxt   K=2048, split-K=4
    gemm_part_atomic32<<<dim3(24, 16, 4), 256, 0, stream>>>(ubf[cb], ctxtbf, nullptr, WgT,
                                                            2048, 512, accF, 1024);
    float* unext = unexts[it];
    gemm_epi<<<3072, 256, 0, stream>>>(accF, B_ * K_ * D_, bg, 3,
                                       unext, ubf[1 - cb], ucurF, ctxtbf);
    cb = 1 - cb;
    ucurF = unext;
    // lr for next scorer               K=1024, split-K=8
    init_lr<<<960, 256, 0, stream>>>(blr, lr);
    gemm_part_atomic32<<<dim3(24, 5, 8), 256, 0, stream>>>(ubf[cb], nullptr, nullptr, WlrT,
                                                           1024, 128, lr, 320);
    if (it == 0){
      (void)hipMemsetAsync(rowsum, 0, (size_t)2 * B_ * K_ * sizeof(float), stream);
      scorer_kernel<<<dim3(K_, 3, B_), 256, 0, stream>>>(lr, dWg, woT, bo, span_begin, span_end,
                                                         outS, 1, mask, pbf, pTbf, rowsum, colsum, 1);
    } else {
      scorer_kernel<<<dim3(K_, 3, B_), 256, 0, stream>>>(lr, dWg, woT, bo, span_begin, span_end,
                                                         outS, 1, mask, pbf, pTbf, rowsum, colsum, 0);
    }
  }

  copy_f4<<<8192, 256, 0, stream>>>((const float4*)all_span, (float4*)outA, (B_ * N_ * D_) / 4);
  // ucurF == outU after it=1 — no final u copy needed
  scatter_kernel<<<B_ * K_, 256, 0, stream>>>(ucurF, prune, span_len, outA);
}

// Round 13
// 502.999 us; speedup vs baseline: 2.6479x; 1.2111x over previous
//
#include <hip/hip_runtime.h>
#include <cmath>

#define B_ 2
#define K_ 384
#define N_ 4096
#define D_ 1024
#define H_ 150
#define L_ 12
#define NB_ 10
#define LDW_S 164   // padded ldw row stride (164 % 32 = 4 dwords -> buckets on distinct banks)

typedef unsigned short u16;
typedef __bf16 bf16x8 __attribute__((ext_vector_type(8)));
typedef float f32x4 __attribute__((ext_vector_type(4)));

__device__ __forceinline__ u16 f2bf(float f){
  unsigned u = __builtin_bit_cast(unsigned, f);
  unsigned r = (u + 0x7FFFu + ((u >> 16) & 1u)) >> 16;
  return (u16)r;
}
__device__ __forceinline__ float bf2f(u16 h){
  unsigned u = ((unsigned)h) << 16;
  return __builtin_bit_cast(float, u);
}
__device__ __forceinline__ int bucketf(int d){
  int da = d < 0 ? -d : d;
  if (da <= 4) return da;
  int lg = 31 - __clz(da);
  int v = lg + 3;
  return v > NB_ - 1 ? NB_ - 1 : v;
}

// ---------------- transpose fp32 (Kd x Nd) -> bf16 (Nd x Kd), out row stride = ostride
__global__ void transpose_f2bf(const float* __restrict__ in, u16* __restrict__ out,
                               int Kd, int Nd, int ostride){
  __shared__ float t[32][33];
  int bx = blockIdx.x * 32, by = blockIdx.y * 32;
  int tx = threadIdx.x, ty = threadIdx.y;
  for (int i = 0; i < 32; i += 8){
    int k = by + ty + i, n = bx + tx;
    t[ty + i][tx] = (k < Kd && n < Nd) ? in[(size_t)k * Nd + n] : 0.f;
  }
  __syncthreads();
  for (int i = 0; i < 32; i += 8){
    int n = bx + ty + i, k = by + tx;
    if (n < Nd && k < Kd) out[(size_t)n * ostride + k] = f2bf(t[tx][ty + i]);
  }
}

// ---------------- transpose bf16 (K_ x D_) -> (D_ x K_) per batch
__global__ void transpose_bf(const u16* __restrict__ in, u16* __restrict__ out){
  __shared__ u16 t[32][34];
  int b = blockIdx.z;
  const u16* I = in + (size_t)b * K_ * D_;
  u16* O = out + (size_t)b * D_ * K_;
  int bx = blockIdx.x * 32, by = blockIdx.y * 32;  // bx: d, by: k
  int tx = threadIdx.x, ty = threadIdx.y;
  for (int i = 0; i < 32; i += 8) t[ty + i][tx] = I[(size_t)(by + ty + i) * D_ + bx + tx];
  __syncthreads();
  for (int i = 0; i < 32; i += 8) O[(size_t)(bx + ty + i) * K_ + by + tx] = t[tx][ty + i];
}

// ---------------- small setup: dW = dist_emb @ Wd + bd ; blr = [bl|br] ; WoT bf16 [16][160]
__global__ void small_setup(const float* __restrict__ dist_emb, const float* __restrict__ Wd,
                            const float* __restrict__ bd, const float* __restrict__ bl,
                            const float* __restrict__ br, const float* __restrict__ Wo,
                            float* __restrict__ dWg, float* __restrict__ blr,
                            u16* __restrict__ woT){
  int tid = threadIdx.x;
  for (int idx = tid; idx < NB_ * H_; idx += 256){
    int nb = idx / H_, h = idx - nb * H_;
    float s = bd[h];
    for (int dd = 0; dd < 20; ++dd) s += dist_emb[nb * 20 + dd] * Wd[dd * H_ + h];
    dWg[idx] = s;
  }
  for (int idx = tid; idx < H_; idx += 256){
    blr[idx] = bl[idx];
    blr[H_ + idx] = br[idx];
  }
  for (int idx = tid; idx < 16 * 160; idx += 256){
    int l = idx / 160, t = idx - l * 160;
    float w = (l < L_ && t < H_) ? Wo[t * L_ + l] : 0.f;
    woT[idx] = f2bf(w);
  }
}

// ---------------- fp32 -> bf16 elementwise (n divisible by 4)
__global__ void cvt_f32_bf16(const float* __restrict__ in, u16* __restrict__ out, int n){
  int idx = (blockIdx.x * 256 + threadIdx.x) * 4;
  if (idx < n){
    float4 v = *(const float4*)(in + idx);
    ushort4 o;
    o.x = f2bf(v.x); o.y = f2bf(v.y); o.z = f2bf(v.z); o.w = f2bf(v.w);
    *(ushort4*)(out + idx) = o;
  }
}

// ---------------- init lr (stride 320): l bias [0,150), r bias [160,310), zeros elsewhere
__global__ void init_lr(const float* __restrict__ blr, float* __restrict__ lr){
  int idx = blockIdx.x * 256 + threadIdx.x;
  if (idx >= (B_ * K_) * 320) return;
  int col = idx % 320;
  float v = 0.f;
  if (col < 150) v = blr[col];
  else if (col >= 160 && col < 310) v = blr[150 + (col - 160)];
  lr[idx] = v;
}

// ---------------- bf16 MFMA GEMM (32x64 tile), split-K atomic; dims must divide exactly
__global__ __launch_bounds__(256)
void gemm_part_atomic32(const u16* __restrict__ A0, const u16* __restrict__ A1,
                        const u16* __restrict__ A2, const u16* __restrict__ BT,
                        int Ktot, int klen, float* __restrict__ Out, int ldo){
  __shared__ u16 As[32][72];
  __shared__ u16 Bs[64][72];
  int tid = threadIdx.x;
  int m0 = blockIdx.x * 32, n0 = blockIdx.y * 64;
  int s = blockIdx.z;
  int kbeg = s * klen, kend = kbeg + klen;
  int wave = tid >> 6, lane = tid & 63;
  int wm = wave >> 1, wn = wave & 1;
  int q = lane >> 4, mr = lane & 15;
  f32x4 acc[2] = {{0.f,0.f,0.f,0.f},{0.f,0.f,0.f,0.f}};
  const u16* Achunks[3] = {A0, A1, A2};
  for (int k0 = kbeg; k0 < kend; k0 += 64){
    const u16* Ap = Achunks[k0 >> 10] + (k0 & 1023);
    {
      int row = tid >> 3, c8 = tid & 7;
      *(uint4*)&As[row][c8 * 8] = *(const uint4*)&Ap[(size_t)(m0 + row) * 1024 + c8 * 8];
    }
    for (int c = tid; c < 512; c += 256){
      int row = c >> 3, c8 = c & 7;
      *(uint4*)&Bs[row][c8 * 8] = *(const uint4*)&BT[(size_t)(n0 + row) * Ktot + k0 + c8 * 8];
    }
    __syncthreads();
#pragma unroll
    for (int ks = 0; ks < 64; ks += 32){
      bf16x8 a  = *(const bf16x8*)&As[wm * 16 + mr][ks + q * 8];
      bf16x8 b0 = *(const bf16x8*)&Bs[wn * 32 + mr][ks + q * 8];
      bf16x8 b1 = *(const bf16x8*)&Bs[wn * 32 + 16 + mr][ks + q * 8];
      acc[0] = __builtin_amdgcn_mfma_f32_16x16x32_bf16(a, b0, acc[0], 0, 0, 0);
      acc[1] = __builtin_amdgcn_mfma_f32_16x16x32_bf16(a, b1, acc[1], 0, 0, 0);
    }
    __syncthreads();
  }
#pragma unroll
  for (int nt = 0; nt < 2; ++nt){
    int col = n0 + wn * 32 + nt * 16 + mr;
#pragma unroll
    for (int r = 0; r < 4; ++r){
      int row = m0 + wm * 16 + q * 4 + r;
      atomicAdd(&Out[(size_t)row * ldo + col], acc[nt][r]);
    }
  }
}

// ---------------- epilogue over fp32 accum (ld = 1024); re-zeros accF for next use
__global__ __launch_bounds__(256)
void gemm_epi(float* __restrict__ accF, int n,
              const float* __restrict__ bias, int mode,
              float* __restrict__ outF, u16* __restrict__ outH,
              const float* __restrict__ uin, const u16* __restrict__ ctxtin){
  int idx = blockIdx.x * 256 + threadIdx.x;
  if (idx >= n) return;
  float ssum = accF[idx];
  accF[idx] = 0.f;                       // self-zero: next split-K GEMM needs zeroed accum
  if (mode == 1){
    outH[idx] = f2bf(tanhf(ssum));
  } else if (mode == 2){
    outH[idx] = f2bf(ssum);
  } else {
    int col = idx & 1023;
    float g = 1.f / (1.f + expf(-(ssum + bias[col])));
    float uo = uin[idx];
    float ct = bf2f(ctxtin[idx]);
    float un = ct + g * (uo - ct);
    outF[idx] = un;
    outH[idx] = f2bf(un);
  }
}

// ---------------- ctxt via MFMA (32x64 tiles, grid 768)
__global__ __launch_bounds__(256)
void ctxt_mfma(const u16* __restrict__ Pbf, const u16* __restrict__ PTbf,
               const u16* __restrict__ uT, const float* __restrict__ rowsum,
               const float* __restrict__ colsum, u16* __restrict__ c1,
               u16* __restrict__ c2){
  __shared__ u16 As[32][72];
  __shared__ u16 Bs[64][72];
  int z = blockIdx.z, b = z >> 1, which = z & 1;
  const u16* A = (which ? PTbf : Pbf) + (size_t)b * K_ * K_;
  const u16* BT = uT + (size_t)b * D_ * K_;
  const float* sums = (which ? colsum : rowsum) + b * K_;
  u16* out = which ? c2 : c1;
  int tid = threadIdx.x;
  int m0 = blockIdx.x * 32, n0 = blockIdx.y * 64;
  int wave = tid >> 6, lane = tid & 63;
  int wm = wave >> 1, wn = wave & 1;
  int q = lane >> 4, mr = lane & 15;
  f32x4 acc[2] = {{0.f,0.f,0.f,0.f},{0.f,0.f,0.f,0.f}};
  for (int k0 = 0; k0 < K_; k0 += 64){
    {
      int row = tid >> 3, c8 = tid & 7;
      *(uint4*)&As[row][c8 * 8] = *(const uint4*)&A[(size_t)(m0 + row) * K_ + k0 + c8 * 8];
    }
    for (int c = tid; c < 512; c += 256){
      int row = c >> 3, c8 = c & 7;
      *(uint4*)&Bs[row][c8 * 8] = *(const uint4*)&BT[(size_t)(n0 + row) * K_ + k0 + c8 * 8];
    }
    __syncthreads();
#pragma unroll
    for (int ks = 0; ks < 64; ks += 32){
      bf16x8 a  = *(const bf16x8*)&As[wm * 16 + mr][ks + q * 8];
      bf16x8 b0 = *(const bf16x8*)&Bs[wn * 32 + mr][ks + q * 8];
      bf16x8 b1 = *(const bf16x8*)&Bs[wn * 32 + 16 + mr][ks + q * 8];
      acc[0] = __builtin_amdgcn_mfma_f32_16x16x32_bf16(a, b0, acc[0], 0, 0, 0);
      acc[1] = __builtin_amdgcn_mfma_f32_16x16x32_bf16(a, b1, acc[1], 0, 0, 0);
    }
    __syncthreads();
  }
#pragma unroll
  for (int nt = 0; nt < 2; ++nt){
    int col = n0 + wn * 32 + nt * 16 + mr;
#pragma unroll
    for (int r = 0; r < 4; ++r){
      int row = m0 + wm * 16 + q * 4 + r;
      float w = 1.f / (sums[row] + 1e-7f);
      out[((size_t)(b * K_ + row)) * D_ + col] = f2bf(acc[nt][r] * w);
    }
  }
}

// ---------------- scorer (MFMA, wave-autonomous; reg-prefetch build, WoT table)
// lr layout: stride 320, l at [0,150), r at [160,310), zeros [310,320)
__global__ __launch_bounds__(256)
void scorer_kernel(const float* __restrict__ lr, const float* __restrict__ dWg,
                   const u16* __restrict__ woT, const float* __restrict__ bo,
                   const int* __restrict__ span_begin, const int* __restrict__ span_end,
                   float* __restrict__ scores, float* __restrict__ maxS, int accumulate){
  __shared__ float ldw[NB_ * LDW_S];
  __shared__ u16 h_s[4][16][168];
  int i = blockIdx.x, jblk = blockIdx.y, b = blockIdx.z;
  int tid = threadIdx.x;
  int row_i = b * K_ + i;
  int se = span_end[row_i];
  // stage ldw = l_i + dW (zero pad t>=150), block-cooperative
  for (int e = tid; e < NB_ * LDW_S; e += 256){
    int nb = e / LDW_S, t = e - nb * LDW_S;
    ldw[e] = (t < H_) ? (lr[(size_t)row_i * 320 + t] + dWg[nb * H_ + t]) : 0.f;
  }
  int wave = tid >> 6, lane = tid & 63;
  int q = lane >> 4, mr = lane & 15;
  // Wo^T fragments from precomputed bf16 table: 5 x dwordx4 loads
  bf16x8 wo_frag[5];
#pragma unroll
  for (int kk = 0; kk < 5; ++kk)
    wo_frag[kk] = *(const bf16x8*)&woT[mr * 160 + kk * 32 + q * 8];
  // zero this wave's h tail cols [150,160)
  for (int e = lane; e < 16 * 5; e += 64){
    int row = e / 5, w5 = e - row * 5;
    *(unsigned*)&h_s[wave][row][150 + w5 * 2] = 0u;
  }
  float bov = (mr < L_) ? bo[mr] : 0.f;
  int rt = lane >> 2, tq = lane & 3;   // build mapping: 4 lanes per row
  __syncthreads();
#pragma unroll
  for (int p = 0; p < 2; ++p){
    int j0w = jblk * 128 + wave * 32 + p * 16;
    // build h bf16 for this wave's 16 rows: prefetch r row into registers (19 batched
    // loads, one waitcnt), then compute. pp==75 reads zeros -> writes zeros (tail).
    {
      int j = j0w + rt;
      int bk = bucketf(span_begin[b * K_ + j] - se);
      const float2* rr = (const float2*)(lr + (size_t)(b * K_ + j) * 320 + 160);
      const float2* lw = (const float2*)(ldw + bk * LDW_S);
      u16* hrow = &h_s[wave][rt][0];
      int pp0 = tq * 19;
      float2 rbuf[19];
#pragma unroll
      for (int s = 0; s < 19; ++s) rbuf[s] = rr[pp0 + s];
#pragma unroll
      for (int s = 0; s < 19; ++s){
        int pp = pp0 + s;
        float2 lv = lw[pp];
        __bf16 h0 = (__bf16)fmaxf(lv.x + rbuf[s].x, 0.f);
        __bf16 h1 = (__bf16)fmaxf(lv.y + rbuf[s].y, 0.f);
        unsigned pk = (unsigned)__builtin_bit_cast(u16, h0) |
                      ((unsigned)__builtin_bit_cast(u16, h1) << 16);
        *(unsigned*)&hrow[pp * 2] = pk;
      }
    }
    // MFMA: 16 j rows x 16 l cols (12 valid), K=160 (intra-wave LDS dep only)
    f32x4 acc = {0.f, 0.f, 0.f, 0.f};
#pragma unroll
    for (int kk = 0; kk < 5; ++kk){
      bf16x8 a = *(const bf16x8*)&h_s[wave][mr][kk * 32 + q * 8];
      acc = __builtin_amdgcn_mfma_f32_16x16x32_bf16(a, wo_frag[kk], acc, 0, 0, 0);
    }
#pragma unroll
    for (int r = 0; r < 4; ++r){
      int j = j0w + q * 4 + r;
      float v = -3.0e38f;
      if (mr < L_){
        size_t addr = ((size_t)row_i * K_ + j) * L_ + mr;
        v = acc[r] + bov;
        if (accumulate) v += scores[addr];
        scores[addr] = v;
      }
      // masked cross-lane max over the 16-lane label group
      float mx = v;
      mx = fmaxf(mx, __shfl_xor(mx, 1, 16));
      mx = fmaxf(mx, __shfl_xor(mx, 2, 16));
      mx = fmaxf(mx, __shfl_xor(mx, 4, 16));
      mx = fmaxf(mx, __shfl_xor(mx, 8, 16));
      if (mr == 0) maxS[(size_t)row_i * K_ + j] = mx;
    }
  }
}

// ---------------- probs from maxS: p = sigmoid(maxS)*mask ; rowsum ; pbf ; pTbf ; colsum
__global__ __launch_bounds__(384)
void probs_kernel(const float* __restrict__ maxS, const float* __restrict__ mask,
                  u16* __restrict__ pbf, u16* __restrict__ pTbf,
                  float* __restrict__ rowsum, float* __restrict__ colsum){
  int i = blockIdx.x, b = blockIdx.y, j = threadIdx.x;
  size_t base = (size_t)(b * K_ + i) * K_ + j;
  float m = maxS[base];
  float p = mask[base] / (1.f + expf(-m));
  u16 ph = f2bf(p);
  pbf[base] = ph;
  pTbf[((size_t)b * K_ + j) * K_ + i] = ph;                 // fused transP
  atomicAdd(&colsum[b * K_ + j], p);                        // fused colsum
  __shared__ float red[6];
  float s = p;
  for (int o = 32; o > 0; o >>= 1) s += __shfl_down(s, o, 64);
  if ((j & 63) == 0) red[j >> 6] = s;
  __syncthreads();
  if (j == 0){
    float tot = 0.f;
    for (int w = 0; w < 6; ++w) tot += red[w];
    rowsum[b * K_ + i] = tot;
  }
}

// ---------------- float4 copy
__global__ void copy_f4(const float4* __restrict__ src, float4* __restrict__ dst, int n){
  int g = blockIdx.x * 256 + threadIdx.x;
  if (g < n) dst[g] = src[g];
}

// ---------------- overwrite_spans scatter (numpy last-wins for duplicate indices)
__global__ void scatter_kernel(const float* __restrict__ u, const int* __restrict__ prune,
                               const int* __restrict__ span_len, float* __restrict__ outA){
  int blk = blockIdx.x;
  int b = blk / K_, k = blk - b * K_;
  int idx = prune[b * K_ + k];
  bool valid = k < span_len[b];
  bool winner = (k == K_ - 1) || (prune[b * K_ + k + 1] != idx);
  if (!(valid && winner)) return;
  const float4* src = (const float4*)(u + ((size_t)b * K_ + k) * D_);
  float4* dst = (float4*)(outA + ((size_t)b * N_ + idx) * D_);
  for (int t = threadIdx.x; t < D_ / 4; t += blockDim.x) dst[t] = src[t];
}

extern "C" void kernel_launch(void* const* d_in, const int* in_sizes, int n_in,
                              void* d_out, int out_size, void* d_ws, size_t ws_size,
                              hipStream_t stream){
  const float* span_vecs = (const float*)d_in[0];
  const float* all_span  = (const float*)d_in[1];
  const int*   span_begin = (const int*)d_in[2];
  const int*   span_end   = (const int*)d_in[3];
  const float* mask       = (const float*)d_in[4];
  const int*   prune      = (const int*)d_in[5];
  const int*   span_len   = (const int*)d_in[6];
  const float* Wl  = (const float*)d_in[8];
  const float* bl  = (const float*)d_in[9];
  const float* Wr  = (const float*)d_in[10];
  const float* br  = (const float*)d_in[11];
  const float* dist_emb = (const float*)d_in[12];
  const float* Wd  = (const float*)d_in[13];
  const float* bd  = (const float*)d_in[14];
  const float* Wo  = (const float*)d_in[15];
  const float* bo  = (const float*)d_in[16];
  const float* Wff1 = (const float*)d_in[17];
  const float* Wff2 = (const float*)d_in[18];
  const float* Wg  = (const float*)d_in[19];
  const float* bg  = (const float*)d_in[20];

  float* outA = (float*)d_out;                       // (B,N,D)
  float* outU = outA + (size_t)B_ * N_ * D_;         // (B,K,D)
  float* outS = outU + (size_t)B_ * K_ * D_;         // (B,K,K,L)

  char* base = (char*)d_ws;
  size_t off = 0;
  auto alloc = [&](size_t bytes) -> void* {
    void* p = base + off;
    off = (off + bytes + 255) & ~((size_t)255);
    return p;
  };
  u16* WlrT  = (u16*)alloc((size_t)320 * 1024 * sizeof(u16));
  u16* Wff1T = (u16*)alloc((size_t)1024 * 3072 * sizeof(u16));
  u16* Wff2T = (u16*)alloc((size_t)1024 * 1024 * sizeof(u16));
  u16* WgT   = (u16*)alloc((size_t)1024 * 2048 * sizeof(u16));
  float* dWg = (float*)alloc(NB_ * H_ * sizeof(float));
  float* blr = (float*)alloc(300 * sizeof(float));
  u16* woT   = (u16*)alloc((size_t)16 * 160 * sizeof(u16));
  float* lr  = (float*)alloc((size_t)B_ * K_ * 320 * sizeof(float));
  float* maxS  = (float*)alloc((size_t)B_ * K_ * K_ * sizeof(float));
  u16* pbf   = (u16*)alloc((size_t)B_ * K_ * K_ * sizeof(u16));
  u16* pTbf  = (u16*)alloc((size_t)B_ * K_ * K_ * sizeof(u16));
  u16* uTbf  = (u16*)alloc((size_t)B_ * D_ * K_ * sizeof(u16));
  float* rowsum = (float*)alloc(B_ * K_ * sizeof(float));
  float* colsum = (float*)alloc(B_ * K_ * sizeof(float));
  u16* ubf0 = (u16*)alloc((size_t)B_ * K_ * D_ * sizeof(u16));
  u16* ubf1 = (u16*)alloc((size_t)B_ * K_ * D_ * sizeof(u16));
  u16* c1bf = (u16*)alloc((size_t)B_ * K_ * D_ * sizeof(u16));
  u16* c2bf = (u16*)alloc((size_t)B_ * K_ * D_ * sizeof(u16));
  u16* tbf  = (u16*)alloc((size_t)B_ * K_ * D_ * sizeof(u16));
  u16* ctxtbf = (u16*)alloc((size_t)B_ * K_ * D_ * sizeof(u16));
  float* uA = (float*)alloc((size_t)B_ * K_ * D_ * sizeof(float));
  float* accF = (float*)alloc((size_t)B_ * K_ * D_ * sizeof(float));  // split-K fp32 accum
  u16* ubf[2] = {ubf0, ubf1};
  (void)ws_size; (void)in_sizes; (void)n_in; (void)out_size;

  dim3 tb(32, 8);
  (void)hipMemsetAsync(WlrT, 0, (size_t)320 * 1024 * sizeof(u16), stream);  // zero pad rows
  transpose_f2bf<<<dim3(5, 32), tb, 0, stream>>>(Wl, WlrT, 1024, 150, 1024);
  transpose_f2bf<<<dim3(5, 32), tb, 0, stream>>>(Wr, WlrT + (size_t)160 * 1024, 1024, 150, 1024);
  transpose_f2bf<<<dim3(32, 96), tb, 0, stream>>>(Wff1, Wff1T, 3072, 1024, 3072);
  transpose_f2bf<<<dim3(32, 32), tb, 0, stream>>>(Wff2, Wff2T, 1024, 1024, 1024);
  transpose_f2bf<<<dim3(32, 64), tb, 0, stream>>>(Wg, WgT, 2048, 1024, 2048);
  small_setup<<<1, 256, 0, stream>>>(dist_emb, Wd, bd, bl, br, Wo, dWg, blr, woT);
  cvt_f32_bf16<<<768, 256, 0, stream>>>(span_vecs, ubf[0], B_ * K_ * D_);
  (void)hipMemsetAsync(accF, 0, (size_t)B_ * K_ * D_ * sizeof(float), stream);  // once; epis self-zero

  // lr = u0 @ [Wl|0|Wr|0] + bias   (split-K=8, 32x64 tiles, 960 blocks, atomic into bias-filled lr)
  init_lr<<<960, 256, 0, stream>>>(blr, lr);
  gemm_part_atomic32<<<dim3(24, 5, 8), 256, 0, stream>>>(ubf[0], nullptr, nullptr, WlrT,
                                                         1024, 128, lr, 320);
  scorer_kernel<<<dim3(K_, 3, B_), 256, 0, stream>>>(lr, dWg, woT, bo, span_begin, span_end,
                                                     outS, maxS, 0);

  const float* ucurF = span_vecs;
  int cb = 0;
  float* unexts[2] = {uA, outU};   // it=1 writes u directly into d_out
  for (int it = 0; it < 2; ++it){
    (void)hipMemsetAsync(colsum, 0, B_ * K_ * sizeof(float), stream);
    probs_kernel<<<dim3(K_, B_), 384, 0, stream>>>(maxS, mask, pbf, pTbf, rowsum, colsum);
    transpose_bf<<<dim3(32, 12, B_), tb, 0, stream>>>(ubf[cb], uTbf);
    ctxt_mfma<<<dim3(12, 16, 2 * B_), 256, 0, stream>>>(pbf, pTbf, uTbf, rowsum, colsum,
                                                        c1bf, c2bf);
    // tbf = tanh(cat(u,c1,c2) @ Wff1)   K=3072, split-K=4, 32x64 tiles (1536 blocks)
    gemm_part_atomic32<<<dim3(24, 16, 4), 256, 0, stream>>>(ubf[cb], c1bf, c2bf, Wff1T,
                                                            3072, 768, accF, 1024);
    gemm_epi<<<3072, 256, 0, stream>>>(accF, B_ * K_ * D_, nullptr, 1,
                                       nullptr, tbf, nullptr, nullptr);
    // ctxt = tbf @ Wff2                 K=1024, split-K=4
    gemm_part_atomic32<<<dim3(24, 16, 4), 256, 0, stream>>>(tbf, nullptr, nullptr, Wff2T,
                                                            1024, 256, accF, 1024);
    gemm_epi<<<3072, 256, 0, stream>>>(accF, B_ * K_ * D_, nullptr, 2,
                                       nullptr, ctxtbf, nullptr, nullptr);
    // gate: g = sigmoid(cat(u,ctxt) @ Wg + bg); un = g*u + (1-g)*ctxt   K=2048, split-K=4
    gemm_part_atomic32<<<dim3(24, 16, 4), 256, 0, stream>>>(ubf[cb], ctxtbf, nullptr, WgT,
                                                            2048, 512, accF, 1024);
    float* unext = unexts[it];
    gemm_epi<<<3072, 256, 0, stream>>>(accF, B_ * K_ * D_, bg, 3,
                                       unext, ubf[1 - cb], ucurF, ctxtbf);
    cb = 1 - cb;
    ucurF = unext;
    // lr for next scorer               K=1024, split-K=8
    init_lr<<<960, 256, 0, stream>>>(blr, lr);
    gemm_part_atomic32<<<dim3(24, 5, 8), 256, 0, stream>>>(ubf[cb], nullptr, nullptr, WlrT,
                                                           1024, 128, lr, 320);
    scorer_kernel<<<dim3(K_, 3, B_), 256, 0, stream>>>(lr, dWg, woT, bo, span_begin, span_end,
                                                       outS, maxS, 1);
  }

  copy_f4<<<8192, 256, 0, stream>>>((const float4*)all_span, (float4*)outA, (B_ * N_ * D_) / 4);
  // ucurF == outU after it=1 — no final u copy needed
  scatter_kernel<<<B_ * K_, 256, 0, stream>>>(ucurF, prune, span_len, outA);
}

// Round 14
// 496.034 us; speedup vs baseline: 2.6851x; 1.0140x over previous
//
#include <hip/hip_runtime.h>
#include <cmath>

#define B_ 2
#define K_ 384
#define N_ 4096
#define D_ 1024
#define H_ 150
#define L_ 12
#define NB_ 10
#define LDW_S 164   // padded ldw row stride (164 % 32 = 4 dwords -> buckets on distinct banks)

typedef unsigned short u16;
typedef __bf16 bf16x8 __attribute__((ext_vector_type(8)));
typedef float f32x4 __attribute__((ext_vector_type(4)));

__device__ __forceinline__ u16 f2bf(float f){
  unsigned u = __builtin_bit_cast(unsigned, f);
  unsigned r = (u + 0x7FFFu + ((u >> 16) & 1u)) >> 16;
  return (u16)r;
}
__device__ __forceinline__ float bf2f(u16 h){
  unsigned u = ((unsigned)h) << 16;
  return __builtin_bit_cast(float, u);
}
__device__ __forceinline__ int bucketf(int d){
  int da = d < 0 ? -d : d;
  if (da <= 4) return da;
  int lg = 31 - __clz(da);
  int v = lg + 3;
  return v > NB_ - 1 ? NB_ - 1 : v;
}

// ---------------- transpose fp32 (Kd x Nd) -> bf16 (Nd x Kd), out row stride = ostride
__global__ void transpose_f2bf(const float* __restrict__ in, u16* __restrict__ out,
                               int Kd, int Nd, int ostride){
  __shared__ float t[32][33];
  int bx = blockIdx.x * 32, by = blockIdx.y * 32;
  int tx = threadIdx.x, ty = threadIdx.y;
  for (int i = 0; i < 32; i += 8){
    int k = by + ty + i, n = bx + tx;
    t[ty + i][tx] = (k < Kd && n < Nd) ? in[(size_t)k * Nd + n] : 0.f;
  }
  __syncthreads();
  for (int i = 0; i < 32; i += 8){
    int n = bx + ty + i, k = by + tx;
    if (n < Nd && k < Kd) out[(size_t)n * ostride + k] = f2bf(t[tx][ty + i]);
  }
}

// ---------------- transpose bf16 (K_ x D_) -> (D_ x K_) per batch
__global__ void transpose_bf(const u16* __restrict__ in, u16* __restrict__ out){
  __shared__ u16 t[32][34];
  int b = blockIdx.z;
  const u16* I = in + (size_t)b * K_ * D_;
  u16* O = out + (size_t)b * D_ * K_;
  int bx = blockIdx.x * 32, by = blockIdx.y * 32;  // bx: d, by: k
  int tx = threadIdx.x, ty = threadIdx.y;
  for (int i = 0; i < 32; i += 8) t[ty + i][tx] = I[(size_t)(by + ty + i) * D_ + bx + tx];
  __syncthreads();
  for (int i = 0; i < 32; i += 8) O[(size_t)(bx + ty + i) * K_ + by + tx] = t[tx][ty + i];
}

// ---------------- small setup: dW = dist_emb @ Wd + bd ; blr = [bl|br] ; WoT bf16 [16][160]
__global__ void small_setup(const float* __restrict__ dist_emb, const float* __restrict__ Wd,
                            const float* __restrict__ bd, const float* __restrict__ bl,
                            const float* __restrict__ br, const float* __restrict__ Wo,
                            float* __restrict__ dWg, float* __restrict__ blr,
                            u16* __restrict__ woT){
  int tid = threadIdx.x;
  for (int idx = tid; idx < NB_ * H_; idx += 256){
    int nb = idx / H_, h = idx - nb * H_;
    float s = bd[h];
    for (int dd = 0; dd < 20; ++dd) s += dist_emb[nb * 20 + dd] * Wd[dd * H_ + h];
    dWg[idx] = s;
  }
  for (int idx = tid; idx < H_; idx += 256){
    blr[idx] = bl[idx];
    blr[H_ + idx] = br[idx];
  }
  for (int idx = tid; idx < 16 * 160; idx += 256){
    int l = idx / 160, t = idx - l * 160;
    float w = (l < L_ && t < H_) ? Wo[t * L_ + l] : 0.f;
    woT[idx] = f2bf(w);
  }
}

// ---------------- fp32 -> bf16 elementwise (n divisible by 4)
__global__ void cvt_f32_bf16(const float* __restrict__ in, u16* __restrict__ out, int n){
  int idx = (blockIdx.x * 256 + threadIdx.x) * 4;
  if (idx < n){
    float4 v = *(const float4*)(in + idx);
    ushort4 o;
    o.x = f2bf(v.x); o.y = f2bf(v.y); o.z = f2bf(v.z); o.w = f2bf(v.w);
    *(ushort4*)(out + idx) = o;
  }
}

// ---------------- init lr (stride 320): l bias [0,150), r bias [160,310), zeros elsewhere
__global__ void init_lr(const float* __restrict__ blr, float* __restrict__ lr){
  int idx = blockIdx.x * 256 + threadIdx.x;
  if (idx >= (B_ * K_) * 320) return;
  int col = idx % 320;
  float v = 0.f;
  if (col < 150) v = blr[col];
  else if (col >= 160 && col < 310) v = blr[150 + (col - 160)];
  lr[idx] = v;
}

// ---------------- bf16 MFMA GEMM (32x64 tile), split-K atomic; dims must divide exactly
__global__ __launch_bounds__(256)
void gemm_part_atomic32(const u16* __restrict__ A0, const u16* __restrict__ A1,
                        const u16* __restrict__ A2, const u16* __restrict__ BT,
                        int Ktot, int klen, float* __restrict__ Out, int ldo){
  __shared__ u16 As[32][72];
  __shared__ u16 Bs[64][72];
  int tid = threadIdx.x;
  int m0 = blockIdx.x * 32, n0 = blockIdx.y * 64;
  int s = blockIdx.z;
  int kbeg = s * klen, kend = kbeg + klen;
  int wave = tid >> 6, lane = tid & 63;
  int wm = wave >> 1, wn = wave & 1;
  int q = lane >> 4, mr = lane & 15;
  f32x4 acc[2] = {{0.f,0.f,0.f,0.f},{0.f,0.f,0.f,0.f}};
  const u16* Achunks[3] = {A0, A1, A2};
  for (int k0 = kbeg; k0 < kend; k0 += 64){
    const u16* Ap = Achunks[k0 >> 10] + (k0 & 1023);
    {
      int row = tid >> 3, c8 = tid & 7;
      *(uint4*)&As[row][c8 * 8] = *(const uint4*)&Ap[(size_t)(m0 + row) * 1024 + c8 * 8];
    }
    for (int c = tid; c < 512; c += 256){
      int row = c >> 3, c8 = c & 7;
      *(uint4*)&Bs[row][c8 * 8] = *(const uint4*)&BT[(size_t)(n0 + row) * Ktot + k0 + c8 * 8];
    }
    __syncthreads();
#pragma unroll
    for (int ks = 0; ks < 64; ks += 32){
      bf16x8 a  = *(const bf16x8*)&As[wm * 16 + mr][ks + q * 8];
      bf16x8 b0 = *(const bf16x8*)&Bs[wn * 32 + mr][ks + q * 8];
      bf16x8 b1 = *(const bf16x8*)&Bs[wn * 32 + 16 + mr][ks + q * 8];
      acc[0] = __builtin_amdgcn_mfma_f32_16x16x32_bf16(a, b0, acc[0], 0, 0, 0);
      acc[1] = __builtin_amdgcn_mfma_f32_16x16x32_bf16(a, b1, acc[1], 0, 0, 0);
    }
    __syncthreads();
  }
#pragma unroll
  for (int nt = 0; nt < 2; ++nt){
    int col = n0 + wn * 32 + nt * 16 + mr;
#pragma unroll
    for (int r = 0; r < 4; ++r){
      int row = m0 + wm * 16 + q * 4 + r;
      atomicAdd(&Out[(size_t)row * ldo + col], acc[nt][r]);
    }
  }
}

// ---------------- epilogue over fp32 accum (ld = 1024); re-zeros accF for next use
__global__ __launch_bounds__(256)
void gemm_epi(float* __restrict__ accF, int n,
              const float* __restrict__ bias, int mode,
              float* __restrict__ outF, u16* __restrict__ outH,
              const float* __restrict__ uin, const u16* __restrict__ ctxtin){
  int idx = blockIdx.x * 256 + threadIdx.x;
  if (idx >= n) return;
  float ssum = accF[idx];
  accF[idx] = 0.f;                       // self-zero: next split-K GEMM needs zeroed accum
  if (mode == 1){
    outH[idx] = f2bf(tanhf(ssum));
  } else if (mode == 2){
    outH[idx] = f2bf(ssum);
  } else {
    int col = idx & 1023;
    float g = 1.f / (1.f + expf(-(ssum + bias[col])));
    float uo = uin[idx];
    float ct = bf2f(ctxtin[idx]);
    float un = ct + g * (uo - ct);
    outF[idx] = un;
    outH[idx] = f2bf(un);
  }
}

// ---------------- ctxt via MFMA (32x64 tiles, grid 768)
__global__ __launch_bounds__(256)
void ctxt_mfma(const u16* __restrict__ Pbf, const u16* __restrict__ PTbf,
               const u16* __restrict__ uT, const float* __restrict__ rowsum,
               const float* __restrict__ colsum, u16* __restrict__ c1,
               u16* __restrict__ c2){
  __shared__ u16 As[32][72];
  __shared__ u16 Bs[64][72];
  int z = blockIdx.z, b = z >> 1, which = z & 1;
  const u16* A = (which ? PTbf : Pbf) + (size_t)b * K_ * K_;
  const u16* BT = uT + (size_t)b * D_ * K_;
  const float* sums = (which ? colsum : rowsum) + b * K_;
  u16* out = which ? c2 : c1;
  int tid = threadIdx.x;
  int m0 = blockIdx.x * 32, n0 = blockIdx.y * 64;
  int wave = tid >> 6, lane = tid & 63;
  int wm = wave >> 1, wn = wave & 1;
  int q = lane >> 4, mr = lane & 15;
  f32x4 acc[2] = {{0.f,0.f,0.f,0.f},{0.f,0.f,0.f,0.f}};
  for (int k0 = 0; k0 < K_; k0 += 64){
    {
      int row = tid >> 3, c8 = tid & 7;
      *(uint4*)&As[row][c8 * 8] = *(const uint4*)&A[(size_t)(m0 + row) * K_ + k0 + c8 * 8];
    }
    for (int c = tid; c < 512; c += 256){
      int row = c >> 3, c8 = c & 7;
      *(uint4*)&Bs[row][c8 * 8] = *(const uint4*)&BT[(size_t)(n0 + row) * K_ + k0 + c8 * 8];
    }
    __syncthreads();
#pragma unroll
    for (int ks = 0; ks < 64; ks += 32){
      bf16x8 a  = *(const bf16x8*)&As[wm * 16 + mr][ks + q * 8];
      bf16x8 b0 = *(const bf16x8*)&Bs[wn * 32 + mr][ks + q * 8];
      bf16x8 b1 = *(const bf16x8*)&Bs[wn * 32 + 16 + mr][ks + q * 8];
      acc[0] = __builtin_amdgcn_mfma_f32_16x16x32_bf16(a, b0, acc[0], 0, 0, 0);
      acc[1] = __builtin_amdgcn_mfma_f32_16x16x32_bf16(a, b1, acc[1], 0, 0, 0);
    }
    __syncthreads();
  }
#pragma unroll
  for (int nt = 0; nt < 2; ++nt){
    int col = n0 + wn * 32 + nt * 16 + mr;
#pragma unroll
    for (int r = 0; r < 4; ++r){
      int row = m0 + wm * 16 + q * 4 + r;
      float w = 1.f / (sums[row] + 1e-7f);
      out[((size_t)(b * K_ + row)) * D_ + col] = f2bf(acc[nt][r] * w);
    }
  }
}

// ---------------- scorer (MFMA, wave-autonomous; all-j-per-block, zero dispatch tail)
// grid (K, B) = 768 blocks, all co-resident. Each wave owns 96 j rows (6 passes of 16).
// lr layout: stride 320, l at [0,150), r at [160,310), zeros [310,320)
__global__ __launch_bounds__(256)
void scorer_kernel(const float* __restrict__ lr, const float* __restrict__ dWg,
                   const u16* __restrict__ woT, const float* __restrict__ bo,
                   const int* __restrict__ span_begin, const int* __restrict__ span_end,
                   float* __restrict__ scores, float* __restrict__ maxS, int accumulate){
  __shared__ float ldw[NB_ * LDW_S];
  __shared__ u16 h_s[4][16][168];
  int i = blockIdx.x, b = blockIdx.y;
  int tid = threadIdx.x;
  int row_i = b * K_ + i;
  int se = span_end[row_i];
  // stage ldw = l_i + dW (zero pad t>=150), block-cooperative (amortized over all 384 j)
  for (int e = tid; e < NB_ * LDW_S; e += 256){
    int nb = e / LDW_S, t = e - nb * LDW_S;
    ldw[e] = (t < H_) ? (lr[(size_t)row_i * 320 + t] + dWg[nb * H_ + t]) : 0.f;
  }
  int wave = tid >> 6, lane = tid & 63;
  int q = lane >> 4, mr = lane & 15;
  // Wo^T fragments from precomputed bf16 table: 5 x dwordx4 loads
  bf16x8 wo_frag[5];
#pragma unroll
  for (int kk = 0; kk < 5; ++kk)
    wo_frag[kk] = *(const bf16x8*)&woT[mr * 160 + kk * 32 + q * 8];
  // zero this wave's h tail cols [150,160)
  for (int e = lane; e < 16 * 5; e += 64){
    int row = e / 5, w5 = e - row * 5;
    *(unsigned*)&h_s[wave][row][150 + w5 * 2] = 0u;
  }
  float bov = (mr < L_) ? bo[mr] : 0.f;
  int rt = lane >> 2, tq = lane & 3;   // build mapping: 4 lanes per row
  __syncthreads();
#pragma unroll
  for (int p = 0; p < 6; ++p){
    int j0w = wave * 96 + p * 16;
    // build h bf16 for this wave's 16 rows: prefetch r row into registers (19 batched
    // loads, one waitcnt), then compute. pp==75 reads zeros -> writes zeros (tail).
    {
      int j = j0w + rt;
      int bk = bucketf(span_begin[b * K_ + j] - se);
      const float2* rr = (const float2*)(lr + (size_t)(b * K_ + j) * 320 + 160);
      const float2* lw = (const float2*)(ldw + bk * LDW_S);
      u16* hrow = &h_s[wave][rt][0];
      int pp0 = tq * 19;
      float2 rbuf[19];
#pragma unroll
      for (int s = 0; s < 19; ++s) rbuf[s] = rr[pp0 + s];
#pragma unroll
      for (int s = 0; s < 19; ++s){
        int pp = pp0 + s;
        float2 lv = lw[pp];
        __bf16 h0 = (__bf16)fmaxf(lv.x + rbuf[s].x, 0.f);
        __bf16 h1 = (__bf16)fmaxf(lv.y + rbuf[s].y, 0.f);
        unsigned pk = (unsigned)__builtin_bit_cast(u16, h0) |
                      ((unsigned)__builtin_bit_cast(u16, h1) << 16);
        *(unsigned*)&hrow[pp * 2] = pk;
      }
    }
    // MFMA: 16 j rows x 16 l cols (12 valid), K=160 (intra-wave LDS dep only)
    f32x4 acc = {0.f, 0.f, 0.f, 0.f};
#pragma unroll
    for (int kk = 0; kk < 5; ++kk){
      bf16x8 a = *(const bf16x8*)&h_s[wave][mr][kk * 32 + q * 8];
      acc = __builtin_amdgcn_mfma_f32_16x16x32_bf16(a, wo_frag[kk], acc, 0, 0, 0);
    }
#pragma unroll
    for (int r = 0; r < 4; ++r){
      int j = j0w + q * 4 + r;
      float v = -3.0e38f;
      if (mr < L_){
        size_t addr = ((size_t)row_i * K_ + j) * L_ + mr;
        v = acc[r] + bov;
        if (accumulate) v += scores[addr];
        scores[addr] = v;
      }
      // masked cross-lane max over the 16-lane label group
      float mx = v;
      mx = fmaxf(mx, __shfl_xor(mx, 1, 16));
      mx = fmaxf(mx, __shfl_xor(mx, 2, 16));
      mx = fmaxf(mx, __shfl_xor(mx, 4, 16));
      mx = fmaxf(mx, __shfl_xor(mx, 8, 16));
      if (mr == 0) maxS[(size_t)row_i * K_ + j] = mx;
    }
  }
}

// ---------------- probs from maxS: p = sigmoid(maxS)*mask ; rowsum ; pbf ; pTbf ; colsum
__global__ __launch_bounds__(384)
void probs_kernel(const float* __restrict__ maxS, const float* __restrict__ mask,
                  u16* __restrict__ pbf, u16* __restrict__ pTbf,
                  float* __restrict__ rowsum, float* __restrict__ colsum){
  int i = blockIdx.x, b = blockIdx.y, j = threadIdx.x;
  size_t base = (size_t)(b * K_ + i) * K_ + j;
  float m = maxS[base];
  float p = mask[base] / (1.f + expf(-m));
  u16 ph = f2bf(p);
  pbf[base] = ph;
  pTbf[((size_t)b * K_ + j) * K_ + i] = ph;                 // fused transP
  atomicAdd(&colsum[b * K_ + j], p);                        // fused colsum
  __shared__ float red[6];
  float s = p;
  for (int o = 32; o > 0; o >>= 1) s += __shfl_down(s, o, 64);
  if ((j & 63) == 0) red[j >> 6] = s;
  __syncthreads();
  if (j == 0){
    float tot = 0.f;
    for (int w = 0; w < 6; ++w) tot += red[w];
    rowsum[b * K_ + i] = tot;
  }
}

// ---------------- float4 copy
__global__ void copy_f4(const float4* __restrict__ src, float4* __restrict__ dst, int n){
  int g = blockIdx.x * 256 + threadIdx.x;
  if (g < n) dst[g] = src[g];
}

// ---------------- overwrite_spans scatter (numpy last-wins for duplicate indices)
__global__ void scatter_kernel(const float* __restrict__ u, const int* __restrict__ prune,
                               const int* __restrict__ span_len, float* __restrict__ outA){
  int blk = blockIdx.x;
  int b = blk / K_, k = blk - b * K_;
  int idx = prune[b * K_ + k];
  bool valid = k < span_len[b];
  bool winner = (k == K_ - 1) || (prune[b * K_ + k + 1] != idx);
  if (!(valid && winner)) return;
  const float4* src = (const float4*)(u + ((size_t)b * K_ + k) * D_);
  float4* dst = (float4*)(outA + ((size_t)b * N_ + idx) * D_);
  for (int t = threadIdx.x; t < D_ / 4; t += blockDim.x) dst[t] = src[t];
}

extern "C" void kernel_launch(void* const* d_in, const int* in_sizes, int n_in,
                              void* d_out, int out_size, void* d_ws, size_t ws_size,
                              hipStream_t stream){
  const float* span_vecs = (const float*)d_in[0];
  const float* all_span  = (const float*)d_in[1];
  const int*   span_begin = (const int*)d_in[2];
  const int*   span_end   = (const int*)d_in[3];
  const float* mask       = (const float*)d_in[4];
  const int*   prune      = (const int*)d_in[5];
  const int*   span_len   = (const int*)d_in[6];
  const float* Wl  = (const float*)d_in[8];
  const float* bl  = (const float*)d_in[9];
  const float* Wr  = (const float*)d_in[10];
  const float* br  = (const float*)d_in[11];
  const float* dist_emb = (const float*)d_in[12];
  const float* Wd  = (const float*)d_in[13];
  const float* bd  = (const float*)d_in[14];
  const float* Wo  = (const float*)d_in[15];
  const float* bo  = (const float*)d_in[16];
  const float* Wff1 = (const float*)d_in[17];
  const float* Wff2 = (const float*)d_in[18];
  const float* Wg  = (const float*)d_in[19];
  const float* bg  = (const float*)d_in[20];

  float* outA = (float*)d_out;                       // (B,N,D)
  float* outU = outA + (size_t)B_ * N_ * D_;         // (B,K,D)
  float* outS = outU + (size_t)B_ * K_ * D_;         // (B,K,K,L)

  char* base = (char*)d_ws;
  size_t off = 0;
  auto alloc = [&](size_t bytes) -> void* {
    void* p = base + off;
    off = (off + bytes + 255) & ~((size_t)255);
    return p;
  };
  u16* WlrT  = (u16*)alloc((size_t)320 * 1024 * sizeof(u16));
  u16* Wff1T = (u16*)alloc((size_t)1024 * 3072 * sizeof(u16));
  u16* Wff2T = (u16*)alloc((size_t)1024 * 1024 * sizeof(u16));
  u16* WgT   = (u16*)alloc((size_t)1024 * 2048 * sizeof(u16));
  float* dWg = (float*)alloc(NB_ * H_ * sizeof(float));
  float* blr = (float*)alloc(300 * sizeof(float));
  u16* woT   = (u16*)alloc((size_t)16 * 160 * sizeof(u16));
  float* lr  = (float*)alloc((size_t)B_ * K_ * 320 * sizeof(float));
  float* maxS  = (float*)alloc((size_t)B_ * K_ * K_ * sizeof(float));
  u16* pbf   = (u16*)alloc((size_t)B_ * K_ * K_ * sizeof(u16));
  u16* pTbf  = (u16*)alloc((size_t)B_ * K_ * K_ * sizeof(u16));
  u16* uTbf  = (u16*)alloc((size_t)B_ * D_ * K_ * sizeof(u16));
  float* rowsum = (float*)alloc(B_ * K_ * sizeof(float));
  float* colsum = (float*)alloc(B_ * K_ * sizeof(float));
  u16* ubf0 = (u16*)alloc((size_t)B_ * K_ * D_ * sizeof(u16));
  u16* ubf1 = (u16*)alloc((size_t)B_ * K_ * D_ * sizeof(u16));
  u16* c1bf = (u16*)alloc((size_t)B_ * K_ * D_ * sizeof(u16));
  u16* c2bf = (u16*)alloc((size_t)B_ * K_ * D_ * sizeof(u16));
  u16* tbf  = (u16*)alloc((size_t)B_ * K_ * D_ * sizeof(u16));
  u16* ctxtbf = (u16*)alloc((size_t)B_ * K_ * D_ * sizeof(u16));
  float* uA = (float*)alloc((size_t)B_ * K_ * D_ * sizeof(float));
  float* accF = (float*)alloc((size_t)B_ * K_ * D_ * sizeof(float));  // split-K fp32 accum
  u16* ubf[2] = {ubf0, ubf1};
  (void)ws_size; (void)in_sizes; (void)n_in; (void)out_size;

  dim3 tb(32, 8);
  (void)hipMemsetAsync(WlrT, 0, (size_t)320 * 1024 * sizeof(u16), stream);  // zero pad rows
  transpose_f2bf<<<dim3(5, 32), tb, 0, stream>>>(Wl, WlrT, 1024, 150, 1024);
  transpose_f2bf<<<dim3(5, 32), tb, 0, stream>>>(Wr, WlrT + (size_t)160 * 1024, 1024, 150, 1024);
  transpose_f2bf<<<dim3(32, 96), tb, 0, stream>>>(Wff1, Wff1T, 3072, 1024, 3072);
  transpose_f2bf<<<dim3(32, 32), tb, 0, stream>>>(Wff2, Wff2T, 1024, 1024, 1024);
  transpose_f2bf<<<dim3(32, 64), tb, 0, stream>>>(Wg, WgT, 2048, 1024, 2048);
  small_setup<<<1, 256, 0, stream>>>(dist_emb, Wd, bd, bl, br, Wo, dWg, blr, woT);
  cvt_f32_bf16<<<768, 256, 0, stream>>>(span_vecs, ubf[0], B_ * K_ * D_);
  (void)hipMemsetAsync(accF, 0, (size_t)B_ * K_ * D_ * sizeof(float), stream);  // once; epis self-zero

  // lr = u0 @ [Wl|0|Wr|0] + bias   (split-K=8, 32x64 tiles, 960 blocks, atomic into bias-filled lr)
  init_lr<<<960, 256, 0, stream>>>(blr, lr);
  gemm_part_atomic32<<<dim3(24, 5, 8), 256, 0, stream>>>(ubf[0], nullptr, nullptr, WlrT,
                                                         1024, 128, lr, 320);
  scorer_kernel<<<dim3(K_, B_), 256, 0, stream>>>(lr, dWg, woT, bo, span_begin, span_end,
                                                  outS, maxS, 0);

  const float* ucurF = span_vecs;
  int cb = 0;
  float* unexts[2] = {uA, outU};   // it=1 writes u directly into d_out
  for (int it = 0; it < 2; ++it){
    (void)hipMemsetAsync(colsum, 0, B_ * K_ * sizeof(float), stream);
    probs_kernel<<<dim3(K_, B_), 384, 0, stream>>>(maxS, mask, pbf, pTbf, rowsum, colsum);
    transpose_bf<<<dim3(32, 12, B_), tb, 0, stream>>>(ubf[cb], uTbf);
    ctxt_mfma<<<dim3(12, 16, 2 * B_), 256, 0, stream>>>(pbf, pTbf, uTbf, rowsum, colsum,
                                                        c1bf, c2bf);
    // tbf = tanh(cat(u,c1,c2) @ Wff1)   K=3072, split-K=4, 32x64 tiles (1536 blocks)
    gemm_part_atomic32<<<dim3(24, 16, 4), 256, 0, stream>>>(ubf[cb], c1bf, c2bf, Wff1T,
                                                            3072, 768, accF, 1024);
    gemm_epi<<<3072, 256, 0, stream>>>(accF, B_ * K_ * D_, nullptr, 1,
                                       nullptr, tbf, nullptr, nullptr);
    // ctxt = tbf @ Wff2                 K=1024, split-K=4
    gemm_part_atomic32<<<dim3(24, 16, 4), 256, 0, stream>>>(tbf, nullptr, nullptr, Wff2T,
                                                            1024, 256, accF, 1024);
    gemm_epi<<<3072, 256, 0, stream>>>(accF, B_ * K_ * D_, nullptr, 2,
                                       nullptr, ctxtbf, nullptr, nullptr);
    // gate: g = sigmoid(cat(u,ctxt) @ Wg + bg); un = g*u + (1-g)*ctxt   K=2048, split-K=4
    gemm_part_atomic32<<<dim3(24, 16, 4), 256, 0, stream>>>(ubf[cb], ctxtbf, nullptr, WgT,
                                                            2048, 512, accF, 1024);
    float* unext = unexts[it];
    gemm_epi<<<3072, 256, 0, stream>>>(accF, B_ * K_ * D_, bg, 3,
                                       unext, ubf[1 - cb], ucurF, ctxtbf);
    cb = 1 - cb;
    ucurF = unext;
    // lr for next scorer               K=1024, split-K=8
    init_lr<<<960, 256, 0, stream>>>(blr, lr);
    gemm_part_atomic32<<<dim3(24, 5, 8), 256, 0, stream>>>(ubf[cb], nullptr, nullptr, WlrT,
                                                           1024, 128, lr, 320);
    scorer_kernel<<<dim3(K_, B_), 256, 0, stream>>>(lr, dWg, woT, bo, span_begin, span_end,
                                                    outS, maxS, 1);
  }

  copy_f4<<<8192, 256, 0, stream>>>((const float4*)all_span, (float4*)outA, (B_ * N_ * D_) / 4);
  // ucurF == outU after it=1 — no final u copy needed
  scatter_kernel<<<B_ * K_, 256, 0, stream>>>(ucurF, prune, span_len, outA);
}

// Round 15
// 475.852 us; speedup vs baseline: 2.7990x; 1.0424x over previous
//
#include <hip/hip_runtime.h>
#include <cmath>

#define B_ 2
#define K_ 384
#define N_ 4096
#define D_ 1024
#define H_ 150
#define L_ 12
#define NB_ 10
#define LDW_S 164   // padded ldw row stride (164 % 32 = 4 dwords -> buckets on distinct banks)

typedef unsigned short u16;
typedef __bf16 bf16x8 __attribute__((ext_vector_type(8)));
typedef float f32x4 __attribute__((ext_vector_type(4)));

__device__ __forceinline__ u16 f2bf(float f){
  unsigned u = __builtin_bit_cast(unsigned, f);
  unsigned r = (u + 0x7FFFu + ((u >> 16) & 1u)) >> 16;
  return (u16)r;
}
__device__ __forceinline__ float bf2f(u16 h){
  unsigned u = ((unsigned)h) << 16;
  return __builtin_bit_cast(float, u);
}
__device__ __forceinline__ int bucketf(int d){
  int da = d < 0 ? -d : d;
  if (da <= 4) return da;
  int lg = 31 - __clz(da);
  int v = lg + 3;
  return v > NB_ - 1 ? NB_ - 1 : v;
}

// ---------------- transpose bf16 (K_ x D_) -> (D_ x K_) per batch
__global__ void transpose_bf(const u16* __restrict__ in, u16* __restrict__ out){
  __shared__ u16 t[32][34];
  int b = blockIdx.z;
  const u16* I = in + (size_t)b * K_ * D_;
  u16* O = out + (size_t)b * D_ * K_;
  int bx = blockIdx.x * 32, by = blockIdx.y * 32;  // bx: d, by: k
  int tx = threadIdx.x, ty = threadIdx.y;
  for (int i = 0; i < 32; i += 8) t[ty + i][tx] = I[(size_t)(by + ty + i) * D_ + bx + tx];
  __syncthreads();
  for (int i = 0; i < 32; i += 8) O[(size_t)(bx + ty + i) * K_ + by + tx] = t[tx][ty + i];
}

// ---------------- fused setup: 5 weight transposes (+pad rows), cvt, lr bias init,
// small_setup (dWg + woT). Segment-dispatched by blockIdx.x range; 8193 blocks.
__global__ __launch_bounds__(256)
void setup_fused(const float* __restrict__ Wl, const float* __restrict__ Wr,
                 const float* __restrict__ Wff1, const float* __restrict__ Wff2,
                 const float* __restrict__ Wg,
                 u16* __restrict__ WlrT, u16* __restrict__ Wff1T,
                 u16* __restrict__ Wff2T, u16* __restrict__ WgT,
                 const float* __restrict__ span_vecs, u16* __restrict__ ubf0,
                 const float* __restrict__ bl, const float* __restrict__ br,
                 float* __restrict__ lr,
                 const float* __restrict__ dist_emb, const float* __restrict__ Wd,
                 const float* __restrict__ bd, const float* __restrict__ Wo,
                 float* __restrict__ dWg, u16* __restrict__ woT){
  __shared__ float t[32][33];
  int blk = blockIdx.x;
  int tid = threadIdx.x;
  if (blk < 6464){
    // weight transposes: fp32 (Kd x Nd) -> bf16 (NdPad x Kd), rows [Nd,NdPad) zero
    const float* in; u16* out; int Kd, Nd, NdPad, nx, ostride, local;
    if (blk < 160){ in=Wl;  out=WlrT;                       Kd=1024; Nd=150;  NdPad=160;  nx=5;  ostride=1024; local=blk; }
    else if (blk < 320){ in=Wr; out=WlrT+(size_t)160*1024;  Kd=1024; Nd=150;  NdPad=160;  nx=5;  ostride=1024; local=blk-160; }
    else if (blk < 3392){ in=Wff1; out=Wff1T;               Kd=3072; Nd=1024; NdPad=1024; nx=32; ostride=3072; local=blk-320; }
    else if (blk < 4416){ in=Wff2; out=Wff2T;               Kd=1024; Nd=1024; NdPad=1024; nx=32; ostride=1024; local=blk-3392; }
    else { in=Wg; out=WgT;                                  Kd=2048; Nd=1024; NdPad=1024; nx=32; ostride=2048; local=blk-4416; }
    int bx = (local % nx) * 32, by = (local / nx) * 32;
    int tx = tid & 31, ty = tid >> 5;
    for (int i = 0; i < 32; i += 8){
      int k = by + ty + i, n = bx + tx;
      t[ty + i][tx] = (k < Kd && n < Nd) ? in[(size_t)k * Nd + n] : 0.f;
    }
    __syncthreads();
    for (int i = 0; i < 32; i += 8){
      int n = bx + ty + i, k = by + tx;
      if (n < NdPad && k < Kd) out[(size_t)n * ostride + k] = f2bf(t[tx][ty + i]);
    }
  } else if (blk < 7232){
    // span_vecs fp32 -> bf16
    int idx = ((blk - 6464) * 256 + tid) * 4;
    if (idx < B_ * K_ * D_){
      float4 v = *(const float4*)(span_vecs + idx);
      ushort4 o;
      o.x = f2bf(v.x); o.y = f2bf(v.y); o.z = f2bf(v.z); o.w = f2bf(v.w);
      *(ushort4*)(ubf0 + idx) = o;
    }
  } else if (blk < 8192){
    // lr bias init (stride 320): l bias [0,150), r bias [160,310), zeros elsewhere
    int idx = (blk - 7232) * 256 + tid;
    if (idx < (B_ * K_) * 320){
      int col = idx % 320;
      float v = 0.f;
      if (col < 150) v = bl[col];
      else if (col >= 160 && col < 310) v = br[col - 160];
      lr[idx] = v;
    }
  } else {
    // small_setup: dWg = dist_emb @ Wd + bd ; woT bf16 [16][160]
    for (int idx = tid; idx < NB_ * H_; idx += 256){
      int nb = idx / H_, h = idx - nb * H_;
      float s = bd[h];
      for (int dd = 0; dd < 20; ++dd) s += dist_emb[nb * 20 + dd] * Wd[dd * H_ + h];
      dWg[idx] = s;
    }
    for (int idx = tid; idx < 16 * 160; idx += 256){
      int l = idx / 160, tcol = idx - l * 160;
      float w = (l < L_ && tcol < H_) ? Wo[tcol * L_ + l] : 0.f;
      woT[idx] = f2bf(w);
    }
  }
}

// ---------------- bf16 MFMA GEMM (32x64 tile), split-K atomic; dims must divide exactly
__global__ __launch_bounds__(256)
void gemm_part_atomic32(const u16* __restrict__ A0, const u16* __restrict__ A1,
                        const u16* __restrict__ A2, const u16* __restrict__ BT,
                        int Ktot, int klen, float* __restrict__ Out, int ldo){
  __shared__ u16 As[32][72];
  __shared__ u16 Bs[64][72];
  int tid = threadIdx.x;
  int m0 = blockIdx.x * 32, n0 = blockIdx.y * 64;
  int s = blockIdx.z;
  int kbeg = s * klen, kend = kbeg + klen;
  int wave = tid >> 6, lane = tid & 63;
  int wm = wave >> 1, wn = wave & 1;
  int q = lane >> 4, mr = lane & 15;
  f32x4 acc[2] = {{0.f,0.f,0.f,0.f},{0.f,0.f,0.f,0.f}};
  const u16* Achunks[3] = {A0, A1, A2};
  for (int k0 = kbeg; k0 < kend; k0 += 64){
    const u16* Ap = Achunks[k0 >> 10] + (k0 & 1023);
    {
      int row = tid >> 3, c8 = tid & 7;
      *(uint4*)&As[row][c8 * 8] = *(const uint4*)&Ap[(size_t)(m0 + row) * 1024 + c8 * 8];
    }
    for (int c = tid; c < 512; c += 256){
      int row = c >> 3, c8 = c & 7;
      *(uint4*)&Bs[row][c8 * 8] = *(const uint4*)&BT[(size_t)(n0 + row) * Ktot + k0 + c8 * 8];
    }
    __syncthreads();
#pragma unroll
    for (int ks = 0; ks < 64; ks += 32){
      bf16x8 a  = *(const bf16x8*)&As[wm * 16 + mr][ks + q * 8];
      bf16x8 b0 = *(const bf16x8*)&Bs[wn * 32 + mr][ks + q * 8];
      bf16x8 b1 = *(const bf16x8*)&Bs[wn * 32 + 16 + mr][ks + q * 8];
      acc[0] = __builtin_amdgcn_mfma_f32_16x16x32_bf16(a, b0, acc[0], 0, 0, 0);
      acc[1] = __builtin_amdgcn_mfma_f32_16x16x32_bf16(a, b1, acc[1], 0, 0, 0);
    }
    __syncthreads();
  }
#pragma unroll
  for (int nt = 0; nt < 2; ++nt){
    int col = n0 + wn * 32 + nt * 16 + mr;
#pragma unroll
    for (int r = 0; r < 4; ++r){
      int row = m0 + wm * 16 + q * 4 + r;
      atomicAdd(&Out[(size_t)row * ldo + col], acc[nt][r]);
    }
  }
}

// ---------------- epilogue over fp32 accum (ld = 1024); re-zeros accF for next use
// mode 3 additionally re-inits lr with bias pattern (precedes the next lr GEMM)
__global__ __launch_bounds__(256)
void gemm_epi(float* __restrict__ accF, int n,
              const float* __restrict__ bias, int mode,
              float* __restrict__ outF, u16* __restrict__ outH,
              const float* __restrict__ uin, const u16* __restrict__ ctxtin,
              const float* __restrict__ bl, const float* __restrict__ br,
              float* __restrict__ lrInit){
  int idx = blockIdx.x * 256 + threadIdx.x;
  if (idx >= n) return;
  float ssum = accF[idx];
  accF[idx] = 0.f;                       // self-zero: next split-K GEMM needs zeroed accum
  if (mode == 1){
    outH[idx] = f2bf(tanhf(ssum));
  } else if (mode == 2){
    outH[idx] = f2bf(ssum);
  } else {
    int col = idx & 1023;
    float g = 1.f / (1.f + expf(-(ssum + bias[col])));
    float uo = uin[idx];
    float ct = bf2f(ctxtin[idx]);
    float un = ct + g * (uo - ct);
    outF[idx] = un;
    outH[idx] = f2bf(un);
    if (idx < (B_ * K_) * 320){          // fused init_lr for the following lr GEMM
      int lcol = idx % 320;
      float v = 0.f;
      if (lcol < 150) v = bl[lcol];
      else if (lcol >= 160 && lcol < 310) v = br[lcol - 160];
      lrInit[idx] = v;
    }
  }
}

// ---------------- ctxt via MFMA (32x64 tiles, grid 768)
__global__ __launch_bounds__(256)
void ctxt_mfma(const u16* __restrict__ Pbf, const u16* __restrict__ PTbf,
               const u16* __restrict__ uT, const float* __restrict__ rowsum,
               const float* __restrict__ colsum, u16* __restrict__ c1,
               u16* __restrict__ c2){
  __shared__ u16 As[32][72];
  __shared__ u16 Bs[64][72];
  int z = blockIdx.z, b = z >> 1, which = z & 1;
  const u16* A = (which ? PTbf : Pbf) + (size_t)b * K_ * K_;
  const u16* BT = uT + (size_t)b * D_ * K_;
  const float* sums = (which ? colsum : rowsum) + b * K_;
  u16* out = which ? c2 : c1;
  int tid = threadIdx.x;
  int m0 = blockIdx.x * 32, n0 = blockIdx.y * 64;
  int wave = tid >> 6, lane = tid & 63;
  int wm = wave >> 1, wn = wave & 1;
  int q = lane >> 4, mr = lane & 15;
  f32x4 acc[2] = {{0.f,0.f,0.f,0.f},{0.f,0.f,0.f,0.f}};
  for (int k0 = 0; k0 < K_; k0 += 64){
    {
      int row = tid >> 3, c8 = tid & 7;
      *(uint4*)&As[row][c8 * 8] = *(const uint4*)&A[(size_t)(m0 + row) * K_ + k0 + c8 * 8];
    }
    for (int c = tid; c < 512; c += 256){
      int row = c >> 3, c8 = c & 7;
      *(uint4*)&Bs[row][c8 * 8] = *(const uint4*)&BT[(size_t)(n0 + row) * K_ + k0 + c8 * 8];
    }
    __syncthreads();
#pragma unroll
    for (int ks = 0; ks < 64; ks += 32){
      bf16x8 a  = *(const bf16x8*)&As[wm * 16 + mr][ks + q * 8];
      bf16x8 b0 = *(const bf16x8*)&Bs[wn * 32 + mr][ks + q * 8];
      bf16x8 b1 = *(const bf16x8*)&Bs[wn * 32 + 16 + mr][ks + q * 8];
      acc[0] = __builtin_amdgcn_mfma_f32_16x16x32_bf16(a, b0, acc[0], 0, 0, 0);
      acc[1] = __builtin_amdgcn_mfma_f32_16x16x32_bf16(a, b1, acc[1], 0, 0, 0);
    }
    __syncthreads();
  }
#pragma unroll
  for (int nt = 0; nt < 2; ++nt){
    int col = n0 + wn * 32 + nt * 16 + mr;
#pragma unroll
    for (int r = 0; r < 4; ++r){
      int row = m0 + wm * 16 + q * 4 + r;
      float w = 1.f / (sums[row] + 1e-7f);
      out[((size_t)(b * K_ + row)) * D_ + col] = f2bf(acc[nt][r] * w);
    }
  }
}

// ---------------- scorer (MFMA, wave-autonomous; all-j-per-block, zero dispatch tail)
// grid (K, B) = 768 blocks, all co-resident. Each wave owns 96 j rows (6 passes of 16).
// lr layout: stride 320, l at [0,150), r at [160,310), zeros [310,320)
__global__ __launch_bounds__(256)
void scorer_kernel(const float* __restrict__ lr, const float* __restrict__ dWg,
                   const u16* __restrict__ woT, const float* __restrict__ bo,
                   const int* __restrict__ span_begin, const int* __restrict__ span_end,
                   float* __restrict__ scores, float* __restrict__ maxS, int accumulate){
  __shared__ float ldw[NB_ * LDW_S];
  __shared__ u16 h_s[4][16][168];
  int i = blockIdx.x, b = blockIdx.y;
  int tid = threadIdx.x;
  int row_i = b * K_ + i;
  int se = span_end[row_i];
  // stage ldw = l_i + dW (zero pad t>=150), block-cooperative (amortized over all 384 j)
  for (int e = tid; e < NB_ * LDW_S; e += 256){
    int nb = e / LDW_S, t = e - nb * LDW_S;
    ldw[e] = (t < H_) ? (lr[(size_t)row_i * 320 + t] + dWg[nb * H_ + t]) : 0.f;
  }
  int wave = tid >> 6, lane = tid & 63;
  int q = lane >> 4, mr = lane & 15;
  // Wo^T fragments from precomputed bf16 table: 5 x dwordx4 loads
  bf16x8 wo_frag[5];
#pragma unroll
  for (int kk = 0; kk < 5; ++kk)
    wo_frag[kk] = *(const bf16x8*)&woT[mr * 160 + kk * 32 + q * 8];
  // zero this wave's h tail cols [150,160)
  for (int e = lane; e < 16 * 5; e += 64){
    int row = e / 5, w5 = e - row * 5;
    *(unsigned*)&h_s[wave][row][150 + w5 * 2] = 0u;
  }
  float bov = (mr < L_) ? bo[mr] : 0.f;
  int rt = lane >> 2, tq = lane & 3;   // build mapping: 4 lanes per row
  __syncthreads();
#pragma unroll
  for (int p = 0; p < 6; ++p){
    int j0w = wave * 96 + p * 16;
    // build h bf16 for this wave's 16 rows: prefetch r row into registers (19 batched
    // loads, one waitcnt), then compute. pp==75 reads zeros -> writes zeros (tail).
    {
      int j = j0w + rt;
      int bk = bucketf(span_begin[b * K_ + j] - se);
      const float2* rr = (const float2*)(lr + (size_t)(b * K_ + j) * 320 + 160);
      const float2* lw = (const float2*)(ldw + bk * LDW_S);
      u16* hrow = &h_s[wave][rt][0];
      int pp0 = tq * 19;
      float2 rbuf[19];
#pragma unroll
      for (int s = 0; s < 19; ++s) rbuf[s] = rr[pp0 + s];
#pragma unroll
      for (int s = 0; s < 19; ++s){
        int pp = pp0 + s;
        float2 lv = lw[pp];
        __bf16 h0 = (__bf16)fmaxf(lv.x + rbuf[s].x, 0.f);
        __bf16 h1 = (__bf16)fmaxf(lv.y + rbuf[s].y, 0.f);
        unsigned pk = (unsigned)__builtin_bit_cast(u16, h0) |
                      ((unsigned)__builtin_bit_cast(u16, h1) << 16);
        *(unsigned*)&hrow[pp * 2] = pk;
      }
    }
    // MFMA: 16 j rows x 16 l cols (12 valid), K=160 (intra-wave LDS dep only)
    f32x4 acc = {0.f, 0.f, 0.f, 0.f};
#pragma unroll
    for (int kk = 0; kk < 5; ++kk){
      bf16x8 a = *(const bf16x8*)&h_s[wave][mr][kk * 32 + q * 8];
      acc = __builtin_amdgcn_mfma_f32_16x16x32_bf16(a, wo_frag[kk], acc, 0, 0, 0);
    }
#pragma unroll
    for (int r = 0; r < 4; ++r){
      int j = j0w + q * 4 + r;
      float v = -3.0e38f;
      if (mr < L_){
        size_t addr = ((size_t)row_i * K_ + j) * L_ + mr;
        v = acc[r] + bov;
        if (accumulate) v += scores[addr];
        scores[addr] = v;
      }
      // masked cross-lane max over the 16-lane label group
      float mx = v;
      mx = fmaxf(mx, __shfl_xor(mx, 1, 16));
      mx = fmaxf(mx, __shfl_xor(mx, 2, 16));
      mx = fmaxf(mx, __shfl_xor(mx, 4, 16));
      mx = fmaxf(mx, __shfl_xor(mx, 8, 16));
      if (mr == 0) maxS[(size_t)row_i * K_ + j] = mx;
    }
  }
}

// ---------------- probs from maxS: p = sigmoid(maxS)*mask ; rowsum ; pbf ; pTbf ; colsum
__global__ __launch_bounds__(384)
void probs_kernel(const float* __restrict__ maxS, const float* __restrict__ mask,
                  u16* __restrict__ pbf, u16* __restrict__ pTbf,
                  float* __restrict__ rowsum, float* __restrict__ colsum){
  int i = blockIdx.x, b = blockIdx.y, j = threadIdx.x;
  size_t base = (size_t)(b * K_ + i) * K_ + j;
  float m = maxS[base];
  float p = mask[base] / (1.f + expf(-m));
  u16 ph = f2bf(p);
  pbf[base] = ph;
  pTbf[((size_t)b * K_ + j) * K_ + i] = ph;                 // fused transP
  atomicAdd(&colsum[b * K_ + j], p);                        // fused colsum
  __shared__ float red[6];
  float s = p;
  for (int o = 32; o > 0; o >>= 1) s += __shfl_down(s, o, 64);
  if ((j & 63) == 0) red[j >> 6] = s;
  __syncthreads();
  if (j == 0){
    float tot = 0.f;
    for (int w = 0; w < 6; ++w) tot += red[w];
    rowsum[b * K_ + i] = tot;
  }
}

// ---------------- float4 copy
__global__ void copy_f4(const float4* __restrict__ src, float4* __restrict__ dst, int n){
  int g = blockIdx.x * 256 + threadIdx.x;
  if (g < n) dst[g] = src[g];
}

// ---------------- overwrite_spans scatter (numpy last-wins for duplicate indices)
__global__ void scatter_kernel(const float* __restrict__ u, const int* __restrict__ prune,
                               const int* __restrict__ span_len, float* __restrict__ outA){
  int blk = blockIdx.x;
  int b = blk / K_, k = blk - b * K_;
  int idx = prune[b * K_ + k];
  bool valid = k < span_len[b];
  bool winner = (k == K_ - 1) || (prune[b * K_ + k + 1] != idx);
  if (!(valid && winner)) return;
  const float4* src = (const float4*)(u + ((size_t)b * K_ + k) * D_);
  float4* dst = (float4*)(outA + ((size_t)b * N_ + idx) * D_);
  for (int t = threadIdx.x; t < D_ / 4; t += blockDim.x) dst[t] = src[t];
}

extern "C" void kernel_launch(void* const* d_in, const int* in_sizes, int n_in,
                              void* d_out, int out_size, void* d_ws, size_t ws_size,
                              hipStream_t stream){
  const float* span_vecs = (const float*)d_in[0];
  const float* all_span  = (const float*)d_in[1];
  const int*   span_begin = (const int*)d_in[2];
  const int*   span_end   = (const int*)d_in[3];
  const float* mask       = (const float*)d_in[4];
  const int*   prune      = (const int*)d_in[5];
  const int*   span_len   = (const int*)d_in[6];
  const float* Wl  = (const float*)d_in[8];
  const float* bl  = (const float*)d_in[9];
  const float* Wr  = (const float*)d_in[10];
  const float* br  = (const float*)d_in[11];
  const float* dist_emb = (const float*)d_in[12];
  const float* Wd  = (const float*)d_in[13];
  const float* bd  = (const float*)d_in[14];
  const float* Wo  = (const float*)d_in[15];
  const float* bo  = (const float*)d_in[16];
  const float* Wff1 = (const float*)d_in[17];
  const float* Wff2 = (const float*)d_in[18];
  const float* Wg  = (const float*)d_in[19];
  const float* bg  = (const float*)d_in[20];

  float* outA = (float*)d_out;                       // (B,N,D)
  float* outU = outA + (size_t)B_ * N_ * D_;         // (B,K,D)
  float* outS = outU + (size_t)B_ * K_ * D_;         // (B,K,K,L)

  char* base = (char*)d_ws;
  size_t off = 0;
  auto alloc = [&](size_t bytes) -> void* {
    void* p = base + off;
    off = (off + bytes + 255) & ~((size_t)255);
    return p;
  };
  u16* WlrT  = (u16*)alloc((size_t)320 * 1024 * sizeof(u16));
  u16* Wff1T = (u16*)alloc((size_t)1024 * 3072 * sizeof(u16));
  u16* Wff2T = (u16*)alloc((size_t)1024 * 1024 * sizeof(u16));
  u16* WgT   = (u16*)alloc((size_t)1024 * 2048 * sizeof(u16));
  float* dWg = (float*)alloc(NB_ * H_ * sizeof(float));
  u16* woT   = (u16*)alloc((size_t)16 * 160 * sizeof(u16));
  float* lr  = (float*)alloc((size_t)B_ * K_ * 320 * sizeof(float));
  float* maxS  = (float*)alloc((size_t)B_ * K_ * K_ * sizeof(float));
  u16* pbf   = (u16*)alloc((size_t)B_ * K_ * K_ * sizeof(u16));
  u16* pTbf  = (u16*)alloc((size_t)B_ * K_ * K_ * sizeof(u16));
  u16* uTbf  = (u16*)alloc((size_t)B_ * D_ * K_ * sizeof(u16));
  float* rowsum = (float*)alloc(B_ * K_ * sizeof(float));
  float* colsum = (float*)alloc(B_ * K_ * sizeof(float));
  u16* ubf0 = (u16*)alloc((size_t)B_ * K_ * D_ * sizeof(u16));
  u16* ubf1 = (u16*)alloc((size_t)B_ * K_ * D_ * sizeof(u16));
  u16* c1bf = (u16*)alloc((size_t)B_ * K_ * D_ * sizeof(u16));
  u16* c2bf = (u16*)alloc((size_t)B_ * K_ * D_ * sizeof(u16));
  u16* tbf  = (u16*)alloc((size_t)B_ * K_ * D_ * sizeof(u16));
  u16* ctxtbf = (u16*)alloc((size_t)B_ * K_ * D_ * sizeof(u16));
  float* uA = (float*)alloc((size_t)B_ * K_ * D_ * sizeof(float));
  float* accF = (float*)alloc((size_t)B_ * K_ * D_ * sizeof(float));  // split-K fp32 accum
  u16* ubf[2] = {ubf0, ubf1};
  (void)ws_size; (void)in_sizes; (void)n_in; (void)out_size;

  dim3 tb(32, 8);
  // one fused setup launch: all weight transposes (+pad), cvt, lr bias init, small setup
  setup_fused<<<8193, 256, 0, stream>>>(Wl, Wr, Wff1, Wff2, Wg,
                                        WlrT, Wff1T, Wff2T, WgT,
                                        span_vecs, ubf[0], bl, br, lr,
                                        dist_emb, Wd, bd, Wo, dWg, woT);
  (void)hipMemsetAsync(accF, 0, (size_t)B_ * K_ * D_ * sizeof(float), stream);  // once; epis self-zero

  // lr = u0 @ [Wl|0|Wr|0] + bias   (split-K=8, 32x64 tiles, 960 blocks, atomic into bias-filled lr)
  gemm_part_atomic32<<<dim3(24, 5, 8), 256, 0, stream>>>(ubf[0], nullptr, nullptr, WlrT,
                                                         1024, 128, lr, 320);
  scorer_kernel<<<dim3(K_, B_), 256, 0, stream>>>(lr, dWg, woT, bo, span_begin, span_end,
                                                  outS, maxS, 0);

  const float* ucurF = span_vecs;
  int cb = 0;
  float* unexts[2] = {uA, outU};   // it=1 writes u directly into d_out
  for (int it = 0; it < 2; ++it){
    (void)hipMemsetAsync(colsum, 0, B_ * K_ * sizeof(float), stream);
    probs_kernel<<<dim3(K_, B_), 384, 0, stream>>>(maxS, mask, pbf, pTbf, rowsum, colsum);
    transpose_bf<<<dim3(32, 12, B_), tb, 0, stream>>>(ubf[cb], uTbf);
    ctxt_mfma<<<dim3(12, 16, 2 * B_), 256, 0, stream>>>(pbf, pTbf, uTbf, rowsum, colsum,
                                                        c1bf, c2bf);
    // tbf = tanh(cat(u,c1,c2) @ Wff1)   K=3072, split-K=4, 32x64 tiles (1536 blocks)
    gemm_part_atomic32<<<dim3(24, 16, 4), 256, 0, stream>>>(ubf[cb], c1bf, c2bf, Wff1T,
                                                            3072, 768, accF, 1024);
    gemm_epi<<<3072, 256, 0, stream>>>(accF, B_ * K_ * D_, nullptr, 1,
                                       nullptr, tbf, nullptr, nullptr,
                                       nullptr, nullptr, nullptr);
    // ctxt = tbf @ Wff2                 K=1024, split-K=4
    gemm_part_atomic32<<<dim3(24, 16, 4), 256, 0, stream>>>(tbf, nullptr, nullptr, Wff2T,
                                                            1024, 256, accF, 1024);
    gemm_epi<<<3072, 256, 0, stream>>>(accF, B_ * K_ * D_, nullptr, 2,
                                       nullptr, ctxtbf, nullptr, nullptr,
                                       nullptr, nullptr, nullptr);
    // gate: g = sigmoid(cat(u,ctxt) @ Wg + bg); un = g*u + (1-g)*ctxt   K=2048, split-K=4
    gemm_part_atomic32<<<dim3(24, 16, 4), 256, 0, stream>>>(ubf[cb], ctxtbf, nullptr, WgT,
                                                            2048, 512, accF, 1024);
    float* unext = unexts[it];
    // gate epi also re-inits lr with bias (precedes the next lr GEMM)
    gemm_epi<<<3072, 256, 0, stream>>>(accF, B_ * K_ * D_, bg, 3,
                                       unext, ubf[1 - cb], ucurF, ctxtbf,
                                       bl, br, lr);
    cb = 1 - cb;
    ucurF = unext;
    // lr for next scorer               K=1024, split-K=8 (lr pre-initialized by gate epi)
    gemm_part_atomic32<<<dim3(24, 5, 8), 256, 0, stream>>>(ubf[cb], nullptr, nullptr, WlrT,
                                                           1024, 128, lr, 320);
    scorer_kernel<<<dim3(K_, B_), 256, 0, stream>>>(lr, dWg, woT, bo, span_begin, span_end,
                                                    outS, maxS, 1);
  }

  copy_f4<<<8192, 256, 0, stream>>>((const float4*)all_span, (float4*)outA, (B_ * N_ * D_) / 4);
  // ucurF == outU after it=1 — no final u copy needed
  scatter_kernel<<<B_ * K_, 256, 0, stream>>>(ucurF, prune, span_len, outA);
}

// Round 16
// 466.975 us; speedup vs baseline: 2.8522x; 1.0190x over previous
//
#include <hip/hip_runtime.h>
#include <cmath>

#define B_ 2
#define K_ 384
#define N_ 4096
#define D_ 1024
#define H_ 150
#define L_ 12
#define NB_ 10
#define LDW_S 164   // padded ldw row stride (164 % 32 = 4 dwords -> buckets on distinct banks)

typedef unsigned short u16;
typedef __bf16 bf16x8 __attribute__((ext_vector_type(8)));
typedef float f32x4 __attribute__((ext_vector_type(4)));

__device__ __forceinline__ u16 f2bf(float f){
  unsigned u = __builtin_bit_cast(unsigned, f);
  unsigned r = (u + 0x7FFFu + ((u >> 16) & 1u)) >> 16;
  return (u16)r;
}
__device__ __forceinline__ float bf2f(u16 h){
  unsigned u = ((unsigned)h) << 16;
  return __builtin_bit_cast(float, u);
}
__device__ __forceinline__ int bucketf(int d){
  int da = d < 0 ? -d : d;
  if (da <= 4) return da;
  int lg = 31 - __clz(da);
  int v = lg + 3;
  return v > NB_ - 1 ? NB_ - 1 : v;
}

// ---------------- transpose bf16 (K_ x D_) -> (D_ x K_) per batch
__global__ void transpose_bf(const u16* __restrict__ in, u16* __restrict__ out){
  __shared__ u16 t[32][34];
  int b = blockIdx.z;
  const u16* I = in + (size_t)b * K_ * D_;
  u16* O = out + (size_t)b * D_ * K_;
  int bx = blockIdx.x * 32, by = blockIdx.y * 32;  // bx: d, by: k
  int tx = threadIdx.x, ty = threadIdx.y;
  for (int i = 0; i < 32; i += 8) t[ty + i][tx] = I[(size_t)(by + ty + i) * D_ + bx + tx];
  __syncthreads();
  for (int i = 0; i < 32; i += 8) O[(size_t)(bx + ty + i) * K_ + by + tx] = t[tx][ty + i];
}

// ---------------- fused setup: 5 weight transposes (+pad rows), cvt, lr bias init,
// accF zero, small_setup (dWg + woT). Segment-dispatched by blockIdx.x; 11265 blocks.
__global__ __launch_bounds__(256)
void setup_fused(const float* __restrict__ Wl, const float* __restrict__ Wr,
                 const float* __restrict__ Wff1, const float* __restrict__ Wff2,
                 const float* __restrict__ Wg,
                 u16* __restrict__ WlrT, u16* __restrict__ Wff1T,
                 u16* __restrict__ Wff2T, u16* __restrict__ WgT,
                 const float* __restrict__ span_vecs, u16* __restrict__ ubf0,
                 const float* __restrict__ bl, const float* __restrict__ br,
                 float* __restrict__ lr, float* __restrict__ accF,
                 const float* __restrict__ dist_emb, const float* __restrict__ Wd,
                 const float* __restrict__ bd, const float* __restrict__ Wo,
                 float* __restrict__ dWg, u16* __restrict__ woT){
  __shared__ float t[32][33];
  int blk = blockIdx.x;
  int tid = threadIdx.x;
  if (blk < 6464){
    // weight transposes: fp32 (Kd x Nd) -> bf16 (NdPad x Kd), rows [Nd,NdPad) zero
    const float* in; u16* out; int Kd, Nd, NdPad, nx, ostride, local;
    if (blk < 160){ in=Wl;  out=WlrT;                       Kd=1024; Nd=150;  NdPad=160;  nx=5;  ostride=1024; local=blk; }
    else if (blk < 320){ in=Wr; out=WlrT+(size_t)160*1024;  Kd=1024; Nd=150;  NdPad=160;  nx=5;  ostride=1024; local=blk-160; }
    else if (blk < 3392){ in=Wff1; out=Wff1T;               Kd=3072; Nd=1024; NdPad=1024; nx=32; ostride=3072; local=blk-320; }
    else if (blk < 4416){ in=Wff2; out=Wff2T;               Kd=1024; Nd=1024; NdPad=1024; nx=32; ostride=1024; local=blk-3392; }
    else { in=Wg; out=WgT;                                  Kd=2048; Nd=1024; NdPad=1024; nx=32; ostride=2048; local=blk-4416; }
    int bx = (local % nx) * 32, by = (local / nx) * 32;
    int tx = tid & 31, ty = tid >> 5;
    for (int i = 0; i < 32; i += 8){
      int k = by + ty + i, n = bx + tx;
      t[ty + i][tx] = (k < Kd && n < Nd) ? in[(size_t)k * Nd + n] : 0.f;
    }
    __syncthreads();
    for (int i = 0; i < 32; i += 8){
      int n = bx + ty + i, k = by + tx;
      if (n < NdPad && k < Kd) out[(size_t)n * ostride + k] = f2bf(t[tx][ty + i]);
    }
  } else if (blk < 7232){
    // span_vecs fp32 -> bf16
    int idx = ((blk - 6464) * 256 + tid) * 4;
    if (idx < B_ * K_ * D_){
      float4 v = *(const float4*)(span_vecs + idx);
      ushort4 o;
      o.x = f2bf(v.x); o.y = f2bf(v.y); o.z = f2bf(v.z); o.w = f2bf(v.w);
      *(ushort4*)(ubf0 + idx) = o;
    }
  } else if (blk < 8192){
    // lr bias init (stride 320): l bias [0,150), r bias [160,310), zeros elsewhere
    int idx = (blk - 7232) * 256 + tid;
    if (idx < (B_ * K_) * 320){
      int col = idx % 320;
      float v = 0.f;
      if (col < 150) v = bl[col];
      else if (col >= 160 && col < 310) v = br[col - 160];
      lr[idx] = v;
    }
  } else if (blk < 11264){
    // accF zero (epilogues self-zero thereafter within a replay)
    int idx = (blk - 8192) * 256 + tid;
    if (idx < B_ * K_ * D_) accF[idx] = 0.f;
  } else {
    // small_setup: dWg = dist_emb @ Wd + bd ; woT bf16 [16][160]
    for (int idx = tid; idx < NB_ * H_; idx += 256){
      int nb = idx / H_, h = idx - nb * H_;
      float s = bd[h];
      for (int dd = 0; dd < 20; ++dd) s += dist_emb[nb * 20 + dd] * Wd[dd * H_ + h];
      dWg[idx] = s;
    }
    for (int idx = tid; idx < 16 * 160; idx += 256){
      int l = idx / 160, tcol = idx - l * 160;
      float w = (l < L_ && tcol < H_) ? Wo[tcol * L_ + l] : 0.f;
      woT[idx] = f2bf(w);
    }
  }
}

// ---------------- bf16 MFMA GEMM (32x64 tile), split-K atomic; dims must divide exactly
__global__ __launch_bounds__(256)
void gemm_part_atomic32(const u16* __restrict__ A0, const u16* __restrict__ A1,
                        const u16* __restrict__ A2, const u16* __restrict__ BT,
                        int Ktot, int klen, float* __restrict__ Out, int ldo){
  __shared__ u16 As[32][72];
  __shared__ u16 Bs[64][72];
  int tid = threadIdx.x;
  int m0 = blockIdx.x * 32, n0 = blockIdx.y * 64;
  int s = blockIdx.z;
  int kbeg = s * klen, kend = kbeg + klen;
  int wave = tid >> 6, lane = tid & 63;
  int wm = wave >> 1, wn = wave & 1;
  int q = lane >> 4, mr = lane & 15;
  f32x4 acc[2] = {{0.f,0.f,0.f,0.f},{0.f,0.f,0.f,0.f}};
  const u16* Achunks[3] = {A0, A1, A2};
  for (int k0 = kbeg; k0 < kend; k0 += 64){
    const u16* Ap = Achunks[k0 >> 10] + (k0 & 1023);
    {
      int row = tid >> 3, c8 = tid & 7;
      *(uint4*)&As[row][c8 * 8] = *(const uint4*)&Ap[(size_t)(m0 + row) * 1024 + c8 * 8];
    }
    for (int c = tid; c < 512; c += 256){
      int row = c >> 3, c8 = c & 7;
      *(uint4*)&Bs[row][c8 * 8] = *(const uint4*)&BT[(size_t)(n0 + row) * Ktot + k0 + c8 * 8];
    }
    __syncthreads();
#pragma unroll
    for (int ks = 0; ks < 64; ks += 32){
      bf16x8 a  = *(const bf16x8*)&As[wm * 16 + mr][ks + q * 8];
      bf16x8 b0 = *(const bf16x8*)&Bs[wn * 32 + mr][ks + q * 8];
      bf16x8 b1 = *(const bf16x8*)&Bs[wn * 32 + 16 + mr][ks + q * 8];
      acc[0] = __builtin_amdgcn_mfma_f32_16x16x32_bf16(a, b0, acc[0], 0, 0, 0);
      acc[1] = __builtin_amdgcn_mfma_f32_16x16x32_bf16(a, b1, acc[1], 0, 0, 0);
    }
    __syncthreads();
  }
#pragma unroll
  for (int nt = 0; nt < 2; ++nt){
    int col = n0 + wn * 32 + nt * 16 + mr;
#pragma unroll
    for (int r = 0; r < 4; ++r){
      int row = m0 + wm * 16 + q * 4 + r;
      atomicAdd(&Out[(size_t)row * ldo + col], acc[nt][r]);
    }
  }
}

// ---------------- epilogue over fp32 accum (ld = 1024); re-zeros accF for next use
// mode 3 additionally re-inits lr with bias pattern (precedes the next lr GEMM)
__global__ __launch_bounds__(256)
void gemm_epi(float* __restrict__ accF, int n,
              const float* __restrict__ bias, int mode,
              float* __restrict__ outF, u16* __restrict__ outH,
              const float* __restrict__ uin, const u16* __restrict__ ctxtin,
              const float* __restrict__ bl, const float* __restrict__ br,
              float* __restrict__ lrInit){
  int idx = blockIdx.x * 256 + threadIdx.x;
  if (idx >= n) return;
  float ssum = accF[idx];
  accF[idx] = 0.f;                       // self-zero: next split-K GEMM needs zeroed accum
  if (mode == 1){
    outH[idx] = f2bf(tanhf(ssum));
  } else if (mode == 2){
    outH[idx] = f2bf(ssum);
  } else {
    int col = idx & 1023;
    float g = 1.f / (1.f + expf(-(ssum + bias[col])));
    float uo = uin[idx];
    float ct = bf2f(ctxtin[idx]);
    float un = ct + g * (uo - ct);
    outF[idx] = un;
    outH[idx] = f2bf(un);
    if (idx < (B_ * K_) * 320){          // fused init_lr for the following lr GEMM
      int lcol = idx % 320;
      float v = 0.f;
      if (lcol < 150) v = bl[lcol];
      else if (lcol >= 160 && lcol < 310) v = br[lcol - 160];
      lrInit[idx] = v;
    }
  }
}

// ---------------- ctxt via MFMA (32x64 tiles, grid 768)
__global__ __launch_bounds__(256)
void ctxt_mfma(const u16* __restrict__ Pbf, const u16* __restrict__ PTbf,
               const u16* __restrict__ uT, const float* __restrict__ rowsum,
               const float* __restrict__ colsum, u16* __restrict__ c1,
               u16* __restrict__ c2){
  __shared__ u16 As[32][72];
  __shared__ u16 Bs[64][72];
  int z = blockIdx.z, b = z >> 1, which = z & 1;
  const u16* A = (which ? PTbf : Pbf) + (size_t)b * K_ * K_;
  const u16* BT = uT + (size_t)b * D_ * K_;
  const float* sums = (which ? colsum : rowsum) + b * K_;
  u16* out = which ? c2 : c1;
  int tid = threadIdx.x;
  int m0 = blockIdx.x * 32, n0 = blockIdx.y * 64;
  int wave = tid >> 6, lane = tid & 63;
  int wm = wave >> 1, wn = wave & 1;
  int q = lane >> 4, mr = lane & 15;
  f32x4 acc[2] = {{0.f,0.f,0.f,0.f},{0.f,0.f,0.f,0.f}};
  for (int k0 = 0; k0 < K_; k0 += 64){
    {
      int row = tid >> 3, c8 = tid & 7;
      *(uint4*)&As[row][c8 * 8] = *(const uint4*)&A[(size_t)(m0 + row) * K_ + k0 + c8 * 8];
    }
    for (int c = tid; c < 512; c += 256){
      int row = c >> 3, c8 = c & 7;
      *(uint4*)&Bs[row][c8 * 8] = *(const uint4*)&BT[(size_t)(n0 + row) * K_ + k0 + c8 * 8];
    }
    __syncthreads();
#pragma unroll
    for (int ks = 0; ks < 64; ks += 32){
      bf16x8 a  = *(const bf16x8*)&As[wm * 16 + mr][ks + q * 8];
      bf16x8 b0 = *(const bf16x8*)&Bs[wn * 32 + mr][ks + q * 8];
      bf16x8 b1 = *(const bf16x8*)&Bs[wn * 32 + 16 + mr][ks + q * 8];
      acc[0] = __builtin_amdgcn_mfma_f32_16x16x32_bf16(a, b0, acc[0], 0, 0, 0);
      acc[1] = __builtin_amdgcn_mfma_f32_16x16x32_bf16(a, b1, acc[1], 0, 0, 0);
    }
    __syncthreads();
  }
#pragma unroll
  for (int nt = 0; nt < 2; ++nt){
    int col = n0 + wn * 32 + nt * 16 + mr;
#pragma unroll
    for (int r = 0; r < 4; ++r){
      int row = m0 + wm * 16 + q * 4 + r;
      float w = 1.f / (sums[row] + 1e-7f);
      out[((size_t)(b * K_ + row)) * D_ + col] = f2bf(acc[nt][r] * w);
    }
  }
}

// ---------------- scorer (MFMA, wave-autonomous; all-j-per-block, zero dispatch tail)
// grid (K, B) = 768 blocks. Blocks with i==0 also zero colsum (sits between the ctxt
// read and the next probs accumulation — dispatch barriers order it).
__global__ __launch_bounds__(256)
void scorer_kernel(const float* __restrict__ lr, const float* __restrict__ dWg,
                   const u16* __restrict__ woT, const float* __restrict__ bo,
                   const int* __restrict__ span_begin, const int* __restrict__ span_end,
                   float* __restrict__ scores, float* __restrict__ maxS,
                   float* __restrict__ colsum, int accumulate){
  __shared__ float ldw[NB_ * LDW_S];
  __shared__ u16 h_s[4][16][168];
  int i = blockIdx.x, b = blockIdx.y;
  int tid = threadIdx.x;
  int row_i = b * K_ + i;
  int se = span_end[row_i];
  // fused colsum zero for next probs dispatch
  if (i == 0){
    for (int e = tid; e < K_; e += 256) colsum[b * K_ + e] = 0.f;
  }
  // stage ldw = l_i + dW (zero pad t>=150), block-cooperative (amortized over all 384 j)
  for (int e = tid; e < NB_ * LDW_S; e += 256){
    int nb = e / LDW_S, t = e - nb * LDW_S;
    ldw[e] = (t < H_) ? (lr[(size_t)row_i * 320 + t] + dWg[nb * H_ + t]) : 0.f;
  }
  int wave = tid >> 6, lane = tid & 63;
  int q = lane >> 4, mr = lane & 15;
  // Wo^T fragments from precomputed bf16 table: 5 x dwordx4 loads
  bf16x8 wo_frag[5];
#pragma unroll
  for (int kk = 0; kk < 5; ++kk)
    wo_frag[kk] = *(const bf16x8*)&woT[mr * 160 + kk * 32 + q * 8];
  // zero this wave's h tail cols [150,160)
  for (int e = lane; e < 16 * 5; e += 64){
    int row = e / 5, w5 = e - row * 5;
    *(unsigned*)&h_s[wave][row][150 + w5 * 2] = 0u;
  }
  float bov = (mr < L_) ? bo[mr] : 0.f;
  int rt = lane >> 2, tq = lane & 3;   // build mapping: 4 lanes per row
  __syncthreads();
#pragma unroll
  for (int p = 0; p < 6; ++p){
    int j0w = wave * 96 + p * 16;
    // build h bf16 for this wave's 16 rows: prefetch r row into registers (19 batched
    // loads, one waitcnt), then compute. pp==75 reads zeros -> writes zeros (tail).
    {
      int j = j0w + rt;
      int bk = bucketf(span_begin[b * K_ + j] - se);
      const float2* rr = (const float2*)(lr + (size_t)(b * K_ + j) * 320 + 160);
      const float2* lw = (const float2*)(ldw + bk * LDW_S);
      u16* hrow = &h_s[wave][rt][0];
      int pp0 = tq * 19;
      float2 rbuf[19];
#pragma unroll
      for (int s = 0; s < 19; ++s) rbuf[s] = rr[pp0 + s];
#pragma unroll
      for (int s = 0; s < 19; ++s){
        int pp = pp0 + s;
        float2 lv = lw[pp];
        __bf16 h0 = (__bf16)fmaxf(lv.x + rbuf[s].x, 0.f);
        __bf16 h1 = (__bf16)fmaxf(lv.y + rbuf[s].y, 0.f);
        unsigned pk = (unsigned)__builtin_bit_cast(u16, h0) |
                      ((unsigned)__builtin_bit_cast(u16, h1) << 16);
        *(unsigned*)&hrow[pp * 2] = pk;
      }
    }
    // MFMA: 16 j rows x 16 l cols (12 valid), K=160 (intra-wave LDS dep only)
    f32x4 acc = {0.f, 0.f, 0.f, 0.f};
#pragma unroll
    for (int kk = 0; kk < 5; ++kk){
      bf16x8 a = *(const bf16x8*)&h_s[wave][mr][kk * 32 + q * 8];
      acc = __builtin_amdgcn_mfma_f32_16x16x32_bf16(a, wo_frag[kk], acc, 0, 0, 0);
    }
#pragma unroll
    for (int r = 0; r < 4; ++r){
      int j = j0w + q * 4 + r;
      float v = -3.0e38f;
      if (mr < L_){
        size_t addr = ((size_t)row_i * K_ + j) * L_ + mr;
        v = acc[r] + bov;
        if (accumulate) v += scores[addr];
        scores[addr] = v;
      }
      // masked cross-lane max over the 16-lane label group
      float mx = v;
      mx = fmaxf(mx, __shfl_xor(mx, 1, 16));
      mx = fmaxf(mx, __shfl_xor(mx, 2, 16));
      mx = fmaxf(mx, __shfl_xor(mx, 4, 16));
      mx = fmaxf(mx, __shfl_xor(mx, 8, 16));
      if (mr == 0) maxS[(size_t)row_i * K_ + j] = mx;
    }
  }
}

// ---------------- probs from maxS: p = sigmoid(maxS)*mask ; rowsum ; pbf ; pTbf ; colsum
__global__ __launch_bounds__(384)
void probs_kernel(const float* __restrict__ maxS, const float* __restrict__ mask,
                  u16* __restrict__ pbf, u16* __restrict__ pTbf,
                  float* __restrict__ rowsum, float* __restrict__ colsum){
  int i = blockIdx.x, b = blockIdx.y, j = threadIdx.x;
  size_t base = (size_t)(b * K_ + i) * K_ + j;
  float m = maxS[base];
  float p = mask[base] / (1.f + expf(-m));
  u16 ph = f2bf(p);
  pbf[base] = ph;
  pTbf[((size_t)b * K_ + j) * K_ + i] = ph;                 // fused transP
  atomicAdd(&colsum[b * K_ + j], p);                        // fused colsum
  __shared__ float red[6];
  float s = p;
  for (int o = 32; o > 0; o >>= 1) s += __shfl_down(s, o, 64);
  if ((j & 63) == 0) red[j >> 6] = s;
  __syncthreads();
  if (j == 0){
    float tot = 0.f;
    for (int w = 0; w < 6; ++w) tot += red[w];
    rowsum[b * K_ + i] = tot;
  }
}

// ---------------- float4 copy
__global__ void copy_f4(const float4* __restrict__ src, float4* __restrict__ dst, int n){
  int g = blockIdx.x * 256 + threadIdx.x;
  if (g < n) dst[g] = src[g];
}

// ---------------- overwrite_spans scatter (numpy last-wins for duplicate indices)
__global__ void scatter_kernel(const float* __restrict__ u, const int* __restrict__ prune,
                               const int* __restrict__ span_len, float* __restrict__ outA){
  int blk = blockIdx.x;
  int b = blk / K_, k = blk - b * K_;
  int idx = prune[b * K_ + k];
  bool valid = k < span_len[b];
  bool winner = (k == K_ - 1) || (prune[b * K_ + k + 1] != idx);
  if (!(valid && winner)) return;
  const float4* src = (const float4*)(u + ((size_t)b * K_ + k) * D_);
  float4* dst = (float4*)(outA + ((size_t)b * N_ + idx) * D_);
  for (int t = threadIdx.x; t < D_ / 4; t += blockDim.x) dst[t] = src[t];
}

extern "C" void kernel_launch(void* const* d_in, const int* in_sizes, int n_in,
                              void* d_out, int out_size, void* d_ws, size_t ws_size,
                              hipStream_t stream){
  const float* span_vecs = (const float*)d_in[0];
  const float* all_span  = (const float*)d_in[1];
  const int*   span_begin = (const int*)d_in[2];
  const int*   span_end   = (const int*)d_in[3];
  const float* mask       = (const float*)d_in[4];
  const int*   prune      = (const int*)d_in[5];
  const int*   span_len   = (const int*)d_in[6];
  const float* Wl  = (const float*)d_in[8];
  const float* bl  = (const float*)d_in[9];
  const float* Wr  = (const float*)d_in[10];
  const float* br  = (const float*)d_in[11];
  const float* dist_emb = (const float*)d_in[12];
  const float* Wd  = (const float*)d_in[13];
  const float* bd  = (const float*)d_in[14];
  const float* Wo  = (const float*)d_in[15];
  const float* bo  = (const float*)d_in[16];
  const float* Wff1 = (const float*)d_in[17];
  const float* Wff2 = (const float*)d_in[18];
  const float* Wg  = (const float*)d_in[19];
  const float* bg  = (const float*)d_in[20];

  float* outA = (float*)d_out;                       // (B,N,D)
  float* outU = outA + (size_t)B_ * N_ * D_;         // (B,K,D)
  float* outS = outU + (size_t)B_ * K_ * D_;         // (B,K,K,L)

  char* base = (char*)d_ws;
  size_t off = 0;
  auto alloc = [&](size_t bytes) -> void* {
    void* p = base + off;
    off = (off + bytes + 255) & ~((size_t)255);
    return p;
  };
  u16* WlrT  = (u16*)alloc((size_t)320 * 1024 * sizeof(u16));
  u16* Wff1T = (u16*)alloc((size_t)1024 * 3072 * sizeof(u16));
  u16* Wff2T = (u16*)alloc((size_t)1024 * 1024 * sizeof(u16));
  u16* WgT   = (u16*)alloc((size_t)1024 * 2048 * sizeof(u16));
  float* dWg = (float*)alloc(NB_ * H_ * sizeof(float));
  u16* woT   = (u16*)alloc((size_t)16 * 160 * sizeof(u16));
  float* lr  = (float*)alloc((size_t)B_ * K_ * 320 * sizeof(float));
  float* maxS  = (float*)alloc((size_t)B_ * K_ * K_ * sizeof(float));
  u16* pbf   = (u16*)alloc((size_t)B_ * K_ * K_ * sizeof(u16));
  u16* pTbf  = (u16*)alloc((size_t)B_ * K_ * K_ * sizeof(u16));
  u16* uTbf  = (u16*)alloc((size_t)B_ * D_ * K_ * sizeof(u16));
  float* rowsum = (float*)alloc(B_ * K_ * sizeof(float));
  float* colsum = (float*)alloc(B_ * K_ * sizeof(float));
  u16* ubf0 = (u16*)alloc((size_t)B_ * K_ * D_ * sizeof(u16));
  u16* ubf1 = (u16*)alloc((size_t)B_ * K_ * D_ * sizeof(u16));
  u16* c1bf = (u16*)alloc((size_t)B_ * K_ * D_ * sizeof(u16));
  u16* c2bf = (u16*)alloc((size_t)B_ * K_ * D_ * sizeof(u16));
  u16* tbf  = (u16*)alloc((size_t)B_ * K_ * D_ * sizeof(u16));
  u16* ctxtbf = (u16*)alloc((size_t)B_ * K_ * D_ * sizeof(u16));
  float* uA = (float*)alloc((size_t)B_ * K_ * D_ * sizeof(float));
  float* accF = (float*)alloc((size_t)B_ * K_ * D_ * sizeof(float));  // split-K fp32 accum
  u16* ubf[2] = {ubf0, ubf1};
  (void)ws_size; (void)in_sizes; (void)n_in; (void)out_size;

  dim3 tb(32, 8);
  // one fused setup launch: weight transposes (+pad), cvt, lr bias init, accF zero, small setup
  setup_fused<<<11265, 256, 0, stream>>>(Wl, Wr, Wff1, Wff2, Wg,
                                         WlrT, Wff1T, Wff2T, WgT,
                                         span_vecs, ubf[0], bl, br, lr, accF,
                                         dist_emb, Wd, bd, Wo, dWg, woT);

  // lr = u0 @ [Wl|0|Wr|0] + bias   (split-K=8, 32x64 tiles, 960 blocks, atomic into bias-filled lr)
  gemm_part_atomic32<<<dim3(24, 5, 8), 256, 0, stream>>>(ubf[0], nullptr, nullptr, WlrT,
                                                         1024, 128, lr, 320);
  scorer_kernel<<<dim3(K_, B_), 256, 0, stream>>>(lr, dWg, woT, bo, span_begin, span_end,
                                                  outS, maxS, colsum, 0);

  const float* ucurF = span_vecs;
  int cb = 0;
  float* unexts[2] = {uA, outU};   // it=1 writes u directly into d_out
  for (int it = 0; it < 2; ++it){
    probs_kernel<<<dim3(K_, B_), 384, 0, stream>>>(maxS, mask, pbf, pTbf, rowsum, colsum);
    transpose_bf<<<dim3(32, 12, B_), tb, 0, stream>>>(ubf[cb], uTbf);
    ctxt_mfma<<<dim3(12, 16, 2 * B_), 256, 0, stream>>>(pbf, pTbf, uTbf, rowsum, colsum,
                                                        c1bf, c2bf);
    // tbf = tanh(cat(u,c1,c2) @ Wff1)   K=3072, split-K=4, 32x64 tiles (1536 blocks)
    gemm_part_atomic32<<<dim3(24, 16, 4), 256, 0, stream>>>(ubf[cb], c1bf, c2bf, Wff1T,
                                                            3072, 768, accF, 1024);
    gemm_epi<<<3072, 256, 0, stream>>>(accF, B_ * K_ * D_, nullptr, 1,
                                       nullptr, tbf, nullptr, nullptr,
                                       nullptr, nullptr, nullptr);
    // ctxt = tbf @ Wff2                 K=1024, split-K=4
    gemm_part_atomic32<<<dim3(24, 16, 4), 256, 0, stream>>>(tbf, nullptr, nullptr, Wff2T,
                                                            1024, 256, accF, 1024);
    gemm_epi<<<3072, 256, 0, stream>>>(accF, B_ * K_ * D_, nullptr, 2,
                                       nullptr, ctxtbf, nullptr, nullptr,
                                       nullptr, nullptr, nullptr);
    // gate: g = sigmoid(cat(u,ctxt) @ Wg + bg); un = g*u + (1-g)*ctxt   K=2048, split-K=4
    gemm_part_atomic32<<<dim3(24, 16, 4), 256, 0, stream>>>(ubf[cb], ctxtbf, nullptr, WgT,
                                                            2048, 512, accF, 1024);
    float* unext = unexts[it];
    // gate epi also re-inits lr with bias (precedes the next lr GEMM)
    gemm_epi<<<3072, 256, 0, stream>>>(accF, B_ * K_ * D_, bg, 3,
                                       unext, ubf[1 - cb], ucurF, ctxtbf,
                                       bl, br, lr);
    cb = 1 - cb;
    ucurF = unext;
    // lr for next scorer               K=1024, split-K=8 (lr pre-initialized by gate epi)
    gemm_part_atomic32<<<dim3(24, 5, 8), 256, 0, stream>>>(ubf[cb], nullptr, nullptr, WlrT,
                                                           1024, 128, lr, 320);
    scorer_kernel<<<dim3(K_, B_), 256, 0, stream>>>(lr, dWg, woT, bo, span_begin, span_end,
                                                    outS, maxS, colsum, 1);
  }

  copy_f4<<<8192, 256, 0, stream>>>((const float4*)all_span, (float4*)outA, (B_ * N_ * D_) / 4);
  // ucurF == outU after it=1 — no final u copy needed
  scatter_kernel<<<B_ * K_, 256, 0, stream>>>(ucurF, prune, span_len, outA);
}